// Round 15
// baseline (194.492 us; speedup 1.0000x reference)
//
#include <hip/hip_runtime.h>
#include <hip/hip_cooperative_groups.h>
#include <stdint.h>

namespace cg = cooperative_groups;

// Problem constants
#define NB 8
#define HIN 448
#define CH1 256
#define CH2 1024
#define NLOC 1024        // 32*32
#define M2 8192          // NB*NLOC
#define M1 32768         // NB*64*64 conv1 output locations
#define K1 224           // padded im2col K: c*56 + r*8 + cc(0..7), cc==7 -> 0
#define NPTS 12544
#define NOUT 4096
#define CAP 384          // per-batch compacted-row capacity (>= 18*18=324 bound)
#define MC (NB * CAP)    // 3072 compacted conv2 rows
#define M1C (MC * 4)     // 12288 compacted conv1 rows

typedef __attribute__((ext_vector_type(8))) short bf16x8;
typedef __attribute__((ext_vector_type(4))) float f32x4;

__device__ __forceinline__ short f2bf(float f) {
  uint32_t u = __builtin_bit_cast(uint32_t, f);
  uint32_t r = (u + 0x7fffu + ((u >> 16) & 1u)) >> 16;
  return (short)r;
}
__device__ __forceinline__ float bf2f(short s) {
  return __builtin_bit_cast(float, (uint32_t)(uint16_t)s << 16);
}
__device__ __forceinline__ float gelu_f(float x) {
  return 0.5f * x * (1.0f + erff(x * 0.70710678118654752f));
}
__device__ __forceinline__ void gload_lds16(const void* g, void* l) {
  __builtin_amdgcn_global_load_lds((const __attribute__((address_space(1))) unsigned int*)g,
                                   (__attribute__((address_space(3))) unsigned int*)l, 16, 0, 0);
}

// ---- merged: workspace zero + weight cast/permute ----
__global__ void k_prep(const float* __restrict__ c1w, const float* __restrict__ c2w,
                       short* __restrict__ c1wb, short* __restrict__ w2p,
                       float4* __restrict__ zp, int n4) {
  int i = blockIdx.x * 256 + threadIdx.x;
  if (i < n4) zp[i] = make_float4(0.f, 0.f, 0.f, 0.f);
  if (i < CH1 * K1) {
    int o = i / K1, k = i - o * K1;
    int c = k / 56, kk = k - c * 56, r = kk >> 3, cc = kk & 7;
    c1wb[i] = f2bf(cc < 7 ? c1w[((o * 4 + c) * 7 + r) * 7 + cc] : 0.0f);
  }
  if (i < CH2 * CH2) {
    int o = i >> 10, k = i & 1023;
    int pos = k >> 8, ci = k & 255;
    w2p[i] = f2bf(c2w[(size_t)(o * 256 + ci) * 4 + pos]);
  }
}

// ---- point -> bilinear weight accumulation (LDS-aggregated, G12) ----
__global__ __launch_bounds__(256) void k_pts(const float* __restrict__ coords,
                                             float* __restrict__ Aw,
                                             float* __restrict__ cnt,
                                             float* __restrict__ sumAw) {
  __shared__ float lAw[NLOC];
  __shared__ int lcnt;
  __shared__ float wsum[4];
  int t = threadIdx.x;
  int b = blockIdx.x / 49;
  int blk = blockIdx.x - b * 49;
  for (int i = t; i < NLOC; i += 256) lAw[i] = 0.f;
  if (t == 0) lcnt = 0;
  __syncthreads();
  int pi = blk * 256 + t;
  float x = coords[((size_t)b * NPTS + pi) * 2];
  float y = coords[((size_t)b * NPTS + pi) * 2 + 1];
  bool valid = (x >= 0.0f);
  if (valid) {
    float gx = x * 32.0f - 0.5f, gy = y * 32.0f - 0.5f;
    float x0f = floorf(gx), y0f = floorf(gy);
    int x0 = (int)x0f, y0 = (int)y0f;
    float wx1 = gx - x0f, wx0 = 1.0f - wx1;
    float wy1 = gy - y0f, wy0 = 1.0f - wy1;
    int xs[2] = {x0, x0 + 1}, ys[2] = {y0, y0 + 1};
    float wxs[2] = {wx0, wx1}, wys[2] = {wy0, wy1};
    #pragma unroll
    for (int cy = 0; cy < 2; cy++)
      #pragma unroll
      for (int cx = 0; cx < 2; cx++) {
        int ix = xs[cx], iy = ys[cy];
        if (ix >= 0 && ix < 32 && iy >= 0 && iy < 32)
          atomicAdd(&lAw[iy * 32 + ix], wxs[cx] * wys[cy]);
      }
  }
  unsigned long long ball = __ballot(valid);
  if ((t & 63) == 0) atomicAdd(&lcnt, (int)__popcll(ball));
  __syncthreads();
  float tsum = 0.f;
  for (int i = t; i < NLOC; i += 256) {
    float v = lAw[i];
    tsum += v;
    if (v != 0.f) atomicAdd(&Aw[b * NLOC + i], v);
  }
  #pragma unroll
  for (int m = 1; m <= 32; m <<= 1) tsum += __shfl_xor(tsum, m, 64);
  if ((t & 63) == 0) wsum[t >> 6] = tsum;
  __syncthreads();
  if (t == 0) {
    float bs = wsum[0] + wsum[1] + wsum[2] + wsum[3];
    if (bs != 0.f) atomicAdd(&sumAw[b], bs);
    if (lcnt) atomicAdd(&cnt[b], (float)lcnt);
  }
}

// ---- merged: compaction (blocks 0..7) + im2col (blocks 8..519) ----
__global__ __launch_bounds__(256) void k_cim(const float* __restrict__ Aw,
                                             int* __restrict__ idxc,
                                             float* __restrict__ Awc,
                                             const float* __restrict__ images,
                                             const float* __restrict__ masks,
                                             short* __restrict__ A1g) {
  __shared__ float S[28 * 452];
  int t = threadIdx.x;
  if (blockIdx.x < NB) {
    int* cnts = (int*)S;
    int* offs = cnts + 256;
    int b = blockIdx.x;
    int base = b * 1024 + t * 4;
    float w[4];
    int c = 0;
    #pragma unroll
    for (int j = 0; j < 4; j++) { w[j] = Aw[base + j]; c += (w[j] != 0.f) ? 1 : 0; }
    cnts[t] = c;
    offs[t] = c;
    __syncthreads();
    for (int s = 1; s < 256; s <<= 1) {
      int v = (t >= s) ? offs[t - s] : 0;
      __syncthreads();
      offs[t] += v;
      __syncthreads();
    }
    int pos = b * CAP + offs[t] - cnts[t];
    int lim = (b + 1) * CAP;
    #pragma unroll
    for (int j = 0; j < 4; j++)
      if (w[j] != 0.f && pos < lim) { idxc[pos] = base + j; Awc[pos] = w[j]; pos++; }
    int total = offs[255];
    for (int i = total + t; i < CAP; i += 256) {
      idxc[b * CAP + i] = b * 1024;
      Awc[b * CAP + i] = 0.f;
    }
    return;
  }
  int bid = blockIdx.x - NB;
  int b = bid >> 6, y = bid & 63;
  int y7 = y * 7;
  for (int p = t; p < 3136; p += 256) {
    int row = p / 112, c4 = p - row * 112;
    int c = row / 7, r = row - c * 7;
    const float* src = (c < 3)
        ? &images[((size_t)(b * 3 + c) * 448 + y7 + r) * 448 + c4 * 4]
        : &masks[((size_t)b * 448 + y7 + r) * 448 + c4 * 4];
    *(float4*)&S[row * 452 + c4 * 4] = *(const float4*)src;
  }
  __syncthreads();
  size_t obase = (size_t)bid * 64 * K1;
  #pragma unroll
  for (int it = 0; it < 7; it++) {
    int p = it * 256 + t;
    int x = p / 28, k16 = p - x * 28;
    const float* s = &S[k16 * 452 + x * 7];
    short o[8];
    #pragma unroll
    for (int j = 0; j < 7; j++) o[j] = f2bf(s[j]);
    o[7] = 0;
    *(bf16x8*)&A1g[obase + (size_t)p * 8] = *(bf16x8*)o;
  }
}

// ---- 64x64-tile bf16 BT GEMM (conv1c, gathered A rows) ----
template<int KDIM, int LDC, int MODE>
__global__ __launch_bounds__(256) void k_gemm64(
    const short* __restrict__ Amat, const int* __restrict__ idxc,
    const short* __restrict__ Bmat, const float* __restrict__ bias,
    short* __restrict__ Cout) {
  __shared__ __align__(16) char Lraw[16384];
  int t = threadIdx.x, lane = t & 63, wv = t >> 6;
  int mt0 = blockIdx.x * 64;
  int nt0 = blockIdx.y * 64;
  f32x4 acc[2][2];
  #pragma unroll
  for (int i = 0; i < 2; i++)
    #pragma unroll
    for (int j = 0; j < 2; j++) acc[i][j] = (f32x4){0.f, 0.f, 0.f, 0.f};

  int srow = lane >> 2, scol = (lane & 3) * 8;
  int wm = wv >> 1, wn = wv & 1;
  int l15 = lane & 15, lg = lane >> 4;

  int arow = mt0 + wv * 16 + srow;
  const short* Ap;
  if (MODE == 1) {
    int i = arow >> 2, pos = arow & 3;
    int loc = idxc[i];
    int b = loc >> 10, oy = (loc >> 5) & 31, ox = loc & 31;
    int yy = oy * 2 + (pos >> 1), xx = ox * 2 + (pos & 1);
    Ap = Amat + (size_t)((b * 64 + yy) * 64 + xx) * KDIM;
  } else {
    Ap = Amat + (size_t)arow * KDIM;
  }
  const short* Bp = Bmat + (size_t)(nt0 + wv * 16 + srow) * KDIM;

  auto STAGE = [&](int buf, int kt) {
    int k0 = kt * 32;
    char* As = Lraw + buf * 8192;
    char* Bs = As + 4096;
    gload_lds16(Ap + k0 + scol, As + wv * 1024);
    gload_lds16(Bp + k0 + scol, Bs + wv * 1024);
  };

  const int NT = KDIM / 32;
  STAGE(0, 0);
  __syncthreads();
  int cur = 0;
  #pragma unroll 2
  for (int kt = 0; kt < NT; kt++) {
    if (kt + 1 < NT) STAGE(cur ^ 1, kt + 1);
    const short* As = (const short*)(Lraw + cur * 8192);
    const short* Bs = As + 2048;
    bf16x8 af[2], bfr[2];
    #pragma unroll
    for (int i = 0; i < 2; i++)
      af[i] = *(const bf16x8*)&As[(wm * 32 + i * 16 + l15) * 32 + lg * 8];
    #pragma unroll
    for (int j = 0; j < 2; j++)
      bfr[j] = *(const bf16x8*)&Bs[(wn * 32 + j * 16 + l15) * 32 + lg * 8];
    #pragma unroll
    for (int i = 0; i < 2; i++)
      #pragma unroll
      for (int j = 0; j < 2; j++)
        acc[i][j] = __builtin_amdgcn_mfma_f32_16x16x32_bf16(af[i], bfr[j], acc[i][j], 0, 0, 0);
    __syncthreads();
    cur ^= 1;
  }

  short* ct = (short*)Lraw;
  #pragma unroll
  for (int i = 0; i < 2; i++)
    #pragma unroll
    for (int j = 0; j < 2; j++) {
      int cl = wn * 32 + j * 16 + l15;
      float bv = bias[nt0 + cl];
      #pragma unroll
      for (int reg = 0; reg < 4; reg++) {
        int rl = wm * 32 + i * 16 + lg * 4 + reg;
        ct[rl * 68 + cl] = f2bf(acc[i][j][reg] + bv);
      }
    }
  __syncthreads();
  #pragma unroll
  for (int it = 0; it < 2; it++) {
    int p = it * 256 + t;
    int row = p >> 3, cc = (p & 7) * 8;
    bf16x8 v = *(const bf16x8*)&ct[row * 68 + cc];
    *(bf16x8*)&Cout[(size_t)(mt0 + row) * LDC + nt0 + cc] = v;
  }
}

// ---- conv2c: 128x64 tile, K-SPLIT via blockIdx.z (2 halves of 512) ----
// grid (24,16,2) = 768 blocks = 3/CU. f32 partial outputs y2p[z] (L3-resident).
__global__ __launch_bounds__(256) void k_gemm2s(
    const short* __restrict__ Amat, const short* __restrict__ Bmat,
    const float* __restrict__ bias, float* __restrict__ y2p0,
    float* __restrict__ y2p1) {
  const int KDIM = 1024;
  __shared__ __align__(16) char Lraw[24576];
  int t = threadIdx.x, lane = t & 63, wv = t >> 6;
  int mt0 = blockIdx.x * 128;
  int nt0 = blockIdx.y * 64;
  int kz = blockIdx.z;
  int kbase = kz * 512;
  float* outp = kz ? y2p1 : y2p0;
  f32x4 acc[4][2];
  #pragma unroll
  for (int i = 0; i < 4; i++)
    #pragma unroll
    for (int j = 0; j < 2; j++) acc[i][j] = (f32x4){0.f, 0.f, 0.f, 0.f};

  int srow = lane >> 2, scol = (lane & 3) * 8;
  int wm = wv >> 1, wn = wv & 1;
  int l15 = lane & 15, lg = lane >> 4;
  int r0 = wv * 16, r1 = 64 + wv * 16;

  auto STAGE = [&](int buf, int kt) {
    int k0 = kbase + kt * 32;
    char* As = Lraw + buf * 12288;
    char* Bs = As + 8192;
    gload_lds16(&Amat[(size_t)(mt0 + r0 + srow) * KDIM + k0 + scol], As + r0 * 64);
    gload_lds16(&Amat[(size_t)(mt0 + r1 + srow) * KDIM + k0 + scol], As + r1 * 64);
    gload_lds16(&Bmat[(size_t)(nt0 + r0 + srow) * KDIM + k0 + scol], Bs + r0 * 64);
  };

  STAGE(0, 0);
  __syncthreads();
  int cur = 0;
  #pragma unroll 2
  for (int kt = 0; kt < 16; kt++) {
    if (kt + 1 < 16) STAGE(cur ^ 1, kt + 1);
    const short* As = (const short*)(Lraw + cur * 12288);
    const short* Bs = As + 4096;
    bf16x8 af[4], bfr[2];
    #pragma unroll
    for (int i = 0; i < 4; i++)
      af[i] = *(const bf16x8*)&As[(wm * 64 + i * 16 + l15) * 32 + lg * 8];
    #pragma unroll
    for (int j = 0; j < 2; j++)
      bfr[j] = *(const bf16x8*)&Bs[(wn * 32 + j * 16 + l15) * 32 + lg * 8];
    #pragma unroll
    for (int i = 0; i < 4; i++)
      #pragma unroll
      for (int j = 0; j < 2; j++)
        acc[i][j] = __builtin_amdgcn_mfma_f32_16x16x32_bf16(af[i], bfr[j], acc[i][j], 0, 0, 0);
    __syncthreads();
    cur ^= 1;
  }

  #pragma unroll
  for (int i = 0; i < 4; i++)
    #pragma unroll
    for (int j = 0; j < 2; j++) {
      int colg = nt0 + wn * 32 + j * 16 + l15;
      float bv = kz ? 0.0f : bias[colg];
      #pragma unroll
      for (int reg = 0; reg < 4; reg++) {
        int rowg = mt0 + wm * 64 + i * 16 + lg * 4 + reg;
        outp[(size_t)rowg * 1024 + colg] = acc[i][j][reg] + bv;
      }
    }
}

// ---- LN(256)+GELU on compacted conv1 rows (linear layout) ----
__global__ __launch_bounds__(256) void k_ln1c(const short* __restrict__ y1c,
                                              const float* __restrict__ ln1w,
                                              const float* __restrict__ ln1b,
                                              short* __restrict__ act1c) {
  int t = threadIdx.x, wv = t >> 6, lane = t & 63;
  int c = lane * 4;
  float lw[4], lb[4];
  #pragma unroll
  for (int j = 0; j < 4; j++) { lw[j] = ln1w[c + j]; lb[j] = ln1b[c + j]; }
  int j0 = blockIdx.x * 64 + wv * 16;
  for (int r = 0; r < 16; r++) {
    int j = j0 + r;
    short4 v4 = *(const short4*)&y1c[(size_t)j * 256 + c];
    float xs[4] = {bf2f(v4.x), bf2f(v4.y), bf2f(v4.z), bf2f(v4.w)};
    float s = 0.f, q = 0.f;
    #pragma unroll
    for (int jj = 0; jj < 4; jj++) { s += xs[jj]; q += xs[jj] * xs[jj]; }
    #pragma unroll
    for (int mm = 1; mm <= 32; mm <<= 1) { s += __shfl_xor(s, mm, 64); q += __shfl_xor(q, mm, 64); }
    float u = s * (1.0f / 256.0f);
    float rs = rsqrtf(q * (1.0f / 256.0f) - u * u + 1e-6f);
    short o[4];
    #pragma unroll
    for (int jj = 0; jj < 4; jj++) o[jj] = f2bf(gelu_f(lw[jj] * ((xs[jj] - u) * rs) + lb[jj]));
    *(short4*)&act1c[(size_t)j * 256 + c] = make_short4(o[0], o[1], o[2], o[3]);
  }
}

// ---- cooperative tail: poolboth -> red -> mix -> out, one launch ----
__global__ __launch_bounds__(256) void k_tail(
    const float* __restrict__ y2p0, const float* __restrict__ y2p1,
    const float* __restrict__ feat, const int* __restrict__ idxc,
    const float* __restrict__ ln2w, const float* __restrict__ ln2b,
    const float* __restrict__ Awc, float* __restrict__ partials,
    float* __restrict__ partialsF, float* __restrict__ pa,
    float* __restrict__ pf, const float* __restrict__ sumAw,
    const float* __restrict__ cnt, const float* __restrict__ c3w,
    const float* __restrict__ c3b, const float* __restrict__ up_w,
    const float* __restrict__ up_b, float* __restrict__ zn,
    float* __restrict__ out) {
  cg::grid_group grid = cg::this_grid();
  __shared__ float pl[8192];
  int t = threadIdx.x, wv = t >> 6, lane = t & 63;

  // ---- phase A: LN2+GELU+pool over y2p halves AND gathered-feat pool ----
  if (blockIdx.x < 96) {
    int b = blockIdx.x / 12, chunk = blockIdx.x % 12;
    int base = b * CAP + chunk * 32;
    int c0 = lane * 16;
    float lw[16], lb[16], wacc[16], facc[16];
    #pragma unroll
    for (int j = 0; j < 16; j++) {
      lw[j] = ln2w[c0 + j];
      lb[j] = ln2b[c0 + j];
      wacc[j] = 0.f;
      facc[j] = 0.f;
    }
    for (int pass = 0; pass < 8; pass++) {
      int row = base + pass * 4 + wv;
      float wt = Awc[row];
      if (wt == 0.f) continue;
      const float4* fp = (const float4*)(feat + (size_t)idxc[row] * 1024 + c0);
      #pragma unroll
      for (int j = 0; j < 4; j++) {
        float4 v = fp[j];
        facc[j * 4 + 0] += wt * v.x;
        facc[j * 4 + 1] += wt * v.y;
        facc[j * 4 + 2] += wt * v.z;
        facc[j * 4 + 3] += wt * v.w;
      }
      const float4* a0 = (const float4*)(y2p0 + (size_t)row * 1024 + c0);
      const float4* a1 = (const float4*)(y2p1 + (size_t)row * 1024 + c0);
      float xs[16];
      #pragma unroll
      for (int j = 0; j < 4; j++) {
        float4 va = a0[j], vb = a1[j];
        xs[j * 4 + 0] = va.x + vb.x;
        xs[j * 4 + 1] = va.y + vb.y;
        xs[j * 4 + 2] = va.z + vb.z;
        xs[j * 4 + 3] = va.w + vb.w;
      }
      float s = 0.f, q = 0.f;
      #pragma unroll
      for (int j = 0; j < 16; j++) { s += xs[j]; q += xs[j] * xs[j]; }
      #pragma unroll
      for (int m = 1; m <= 32; m <<= 1) { s += __shfl_xor(s, m, 64); q += __shfl_xor(q, m, 64); }
      float u = s * (1.0f / 1024.0f);
      float rs = rsqrtf(q * (1.0f / 1024.0f) - u * u + 1e-6f);
      #pragma unroll
      for (int j = 0; j < 16; j++)
        wacc[j] += wt * gelu_f(lw[j] * ((xs[j] - u) * rs) + lb[j]);
    }
    float* dst = &partials[((size_t)blockIdx.x * 4 + wv) * 1024 + c0];
    float* dstF = &partialsF[((size_t)blockIdx.x * 4 + wv) * 1024 + c0];
    #pragma unroll
    for (int j = 0; j < 4; j++) {
      *(f32x4*)&dst[j * 4] = (f32x4){wacc[j * 4], wacc[j * 4 + 1], wacc[j * 4 + 2], wacc[j * 4 + 3]};
      *(f32x4*)&dstF[j * 4] = (f32x4){facc[j * 4], facc[j * 4 + 1], facc[j * 4 + 2], facc[j * 4 + 3]};
    }
  }
  grid.sync();

  // ---- phase B: reduce 48 partial slots per batch ----
  if (blockIdx.x < 32) {
    int c = blockIdx.x * 256 + t;
    int b = c >> 10, ch = c & 1023;
    const float* p = partials + (size_t)(b * 48) * 1024 + ch;
    const float* pF = partialsF + (size_t)(b * 48) * 1024 + ch;
    float s = 0.f, sf = 0.f;
    #pragma unroll 8
    for (int j = 0; j < 48; j++) {
      s += p[(size_t)j * 1024];
      sf += pF[(size_t)j * 1024];
    }
    pa[c] = s;
    pf[c] = sf;
  }
  grid.sync();

  // ---- phase C: conv3 mix (wave-per-channel, c3w read once) ----
  {
    for (int idx = t; idx < 2048; idx += 256)
      ((float4*)pl)[idx] = ((const float4*)pa)[idx];
    __syncthreads();
    int c = blockIdx.x * 4 + wv;
    float w[16];
    #pragma unroll
    for (int i = 0; i < 16; i++) w[i] = c3w[(size_t)c * 1024 + i * 64 + lane];
    float s[8];
    #pragma unroll
    for (int b = 0; b < 8; b++) s[b] = 0.f;
    #pragma unroll
    for (int i = 0; i < 16; i++) {
      int k = i * 64 + lane;
      #pragma unroll
      for (int b = 0; b < 8; b++) s[b] += w[i] * pl[b * 1024 + k];
    }
    #pragma unroll
    for (int m = 1; m <= 32; m <<= 1)
      #pragma unroll
      for (int b = 0; b < 8; b++) s[b] += __shfl_xor(s[b], m, 64);
    if (lane < 8) {
      float cv = cnt[lane];
      float z = s[lane] + sumAw[lane] * c3b[c] + pf[lane * 1024 + c];
      zn[lane * 1024 + c] = cv > 0.f ? z / cv : 0.f;   // nan_to_num
    }
  }
  grid.sync();

  // ---- phase D: final GEMV, 16 outputs per block (4 per wave) ----
  {
    __syncthreads();
    for (int idx = t; idx < 2048; idx += 256)
      ((float4*)pl)[idx] = ((const float4*)zn)[idx];
    __syncthreads();
    #pragma unroll
    for (int ii = 0; ii < 4; ii++) {
      int o = blockIdx.x * 16 + wv * 4 + ii;
      float w[16];
      #pragma unroll
      for (int i = 0; i < 16; i++) w[i] = up_w[(size_t)o * 1024 + i * 64 + lane];
      float s[8];
      #pragma unroll
      for (int b = 0; b < 8; b++) s[b] = 0.f;
      #pragma unroll
      for (int i = 0; i < 16; i++) {
        int k = i * 64 + lane;
        #pragma unroll
        for (int b = 0; b < 8; b++) s[b] += w[i] * pl[b * 1024 + k];
      }
      #pragma unroll
      for (int m = 1; m <= 32; m <<= 1)
        #pragma unroll
        for (int b = 0; b < 8; b++) s[b] += __shfl_xor(s[b], m, 64);
      if (lane < 8) out[(size_t)lane * NOUT + o] = s[lane] + up_b[o];
    }
  }
}

extern "C" void kernel_launch(void* const* d_in, const int* in_sizes, int n_in,
                              void* d_out, int out_size, void* d_ws, size_t ws_size,
                              hipStream_t stream) {
  const float* images = (const float*)d_in[0];
  const float* masks  = (const float*)d_in[1];
  const float* feat   = (const float*)d_in[2];
  const float* coords = (const float*)d_in[3];
  const float* c1w  = (const float*)d_in[5];
  const float* c1b  = (const float*)d_in[6];
  const float* ln1w = (const float*)d_in[7];
  const float* ln1b = (const float*)d_in[8];
  const float* c2w  = (const float*)d_in[9];
  const float* c2b  = (const float*)d_in[10];
  const float* ln2w = (const float*)d_in[11];
  const float* ln2b = (const float*)d_in[12];
  const float* c3w  = (const float*)d_in[13];
  const float* c3b  = (const float*)d_in[14];
  const float* up_w = (const float*)d_in[15];
  const float* up_b = (const float*)d_in[16];
  float* out = (float*)d_out;

  char* ws = (char*)d_ws;
  size_t off = 0;
  auto alloc = [&](size_t bytes) -> void* {
    void* p = ws + off;
    off = (off + bytes + 255) & ~(size_t)255;
    return p;
  };
  float* Aw    = (float*)alloc(8192 * 4);
  float* cnt   = (float*)alloc(8 * 4);
  float* sumAw = (float*)alloc(8 * 4);
  size_t zeroBytes = off;
  int*   idxc  = (int*)alloc(MC * 4);
  float* Awc   = (float*)alloc(MC * 4);
  float* pa    = (float*)alloc(8192 * 4);
  float* pf    = (float*)alloc(8192 * 4);
  float* partials  = (float*)alloc((size_t)384 * 1024 * 4);
  float* partialsF = (float*)alloc((size_t)384 * 1024 * 4);
  float* zn   = (float*)alloc(8192 * 4);
  short* c1wb = (short*)alloc((size_t)CH1 * K1 * 2);
  short* w2p  = (short*)alloc((size_t)CH2 * CH2 * 2);
  short* A1g  = (short*)alloc((size_t)M1 * K1 * 2);
  short* y1c  = (short*)alloc((size_t)M1C * 256 * 2);
  short* act1c = (short*)alloc((size_t)MC * 1024 * 2);
  float* y2p0 = (float*)alloc((size_t)MC * 1024 * 4);
  float* y2p1 = (float*)alloc((size_t)MC * 1024 * 4);

  int n4 = (int)(zeroBytes / 16);
  k_prep<<<4096, 256, 0, stream>>>(c1w, c2w, c1wb, w2p, (float4*)d_ws, n4);
  k_pts<<<NB * 49, 256, 0, stream>>>(coords, Aw, cnt, sumAw);
  k_cim<<<NB + 512, 256, 0, stream>>>(Aw, idxc, Awc, images, masks, A1g);
  k_gemm64<K1, 256, 1><<<dim3(M1C / 64, 4), 256, 0, stream>>>(A1g, idxc, c1wb, c1b, y1c);
  k_ln1c<<<M1C / 64, 256, 0, stream>>>(y1c, ln1w, ln1b, act1c);
  k_gemm2s<<<dim3(MC / 128, 16, 2), 256, 0, stream>>>(act1c, w2p, c2b, y2p0, y2p1);
  void* targs[] = {&y2p0, &y2p1, (void*)&feat, &idxc, (void*)&ln2w, (void*)&ln2b,
                   &Awc, &partials, &partialsF, &pa, &pf, &sumAw, &cnt,
                   (void*)&c3w, (void*)&c3b, (void*)&up_w, (void*)&up_b, &zn, &out};
  hipLaunchCooperativeKernel((void*)k_tail, dim3(256), dim3(256), targs, 0, stream);
}

// Round 16
// 111.145 us; speedup vs baseline: 1.7499x; 1.7499x over previous
//
#include <hip/hip_runtime.h>
#include <stdint.h>

// Problem constants
#define NB 8
#define HIN 448
#define CH1 256
#define CH2 1024
#define NLOC 1024        // 32*32
#define M2 8192          // NB*NLOC
#define M1 32768         // NB*64*64 conv1 output locations
#define K1 224           // padded im2col K: c*56 + r*8 + cc(0..7), cc==7 -> 0
#define NPTS 12544
#define NOUT 4096
#define CAP 384          // per-batch compacted-row capacity (>= 18*18=324 bound)
#define MC (NB * CAP)    // 3072 compacted conv2 rows
#define M1C (MC * 4)     // 12288 compacted conv1 rows

typedef __attribute__((ext_vector_type(8))) short bf16x8;
typedef __attribute__((ext_vector_type(4))) float f32x4;

__device__ __forceinline__ short f2bf(float f) {
  uint32_t u = __builtin_bit_cast(uint32_t, f);
  uint32_t r = (u + 0x7fffu + ((u >> 16) & 1u)) >> 16;
  return (short)r;
}
__device__ __forceinline__ float bf2f(short s) {
  return __builtin_bit_cast(float, (uint32_t)(uint16_t)s << 16);
}
__device__ __forceinline__ float gelu_f(float x) {
  return 0.5f * x * (1.0f + erff(x * 0.70710678118654752f));
}
__device__ __forceinline__ void gload_lds16(const void* g, void* l) {
  __builtin_amdgcn_global_load_lds((const __attribute__((address_space(1))) unsigned int*)g,
                                   (__attribute__((address_space(3))) unsigned int*)l, 16, 0, 0);
}

// ---- merged: workspace zero + weight cast/permute ----
__global__ void k_prep(const float* __restrict__ c1w, const float* __restrict__ c2w,
                       short* __restrict__ c1wb, short* __restrict__ w2p,
                       float4* __restrict__ zp, int n4) {
  int i = blockIdx.x * 256 + threadIdx.x;
  if (i < n4) zp[i] = make_float4(0.f, 0.f, 0.f, 0.f);
  if (i < CH1 * K1) {
    int o = i / K1, k = i - o * K1;
    int c = k / 56, kk = k - c * 56, r = kk >> 3, cc = kk & 7;
    c1wb[i] = f2bf(cc < 7 ? c1w[((o * 4 + c) * 7 + r) * 7 + cc] : 0.0f);
  }
  if (i < CH2 * CH2) {
    int o = i >> 10, k = i & 1023;
    int pos = k >> 8, ci = k & 255;
    w2p[i] = f2bf(c2w[(size_t)(o * 256 + ci) * 4 + pos]);
  }
}

// ---- point -> bilinear weight accumulation (LDS-aggregated, G12) ----
__global__ __launch_bounds__(256) void k_pts(const float* __restrict__ coords,
                                             float* __restrict__ Aw,
                                             float* __restrict__ cnt,
                                             float* __restrict__ sumAw) {
  __shared__ float lAw[NLOC];
  __shared__ int lcnt;
  __shared__ float wsum[4];
  int t = threadIdx.x;
  int b = blockIdx.x / 49;
  int blk = blockIdx.x - b * 49;
  for (int i = t; i < NLOC; i += 256) lAw[i] = 0.f;
  if (t == 0) lcnt = 0;
  __syncthreads();
  int pi = blk * 256 + t;
  float x = coords[((size_t)b * NPTS + pi) * 2];
  float y = coords[((size_t)b * NPTS + pi) * 2 + 1];
  bool valid = (x >= 0.0f);
  if (valid) {
    float gx = x * 32.0f - 0.5f, gy = y * 32.0f - 0.5f;
    float x0f = floorf(gx), y0f = floorf(gy);
    int x0 = (int)x0f, y0 = (int)y0f;
    float wx1 = gx - x0f, wx0 = 1.0f - wx1;
    float wy1 = gy - y0f, wy0 = 1.0f - wy1;
    int xs[2] = {x0, x0 + 1}, ys[2] = {y0, y0 + 1};
    float wxs[2] = {wx0, wx1}, wys[2] = {wy0, wy1};
    #pragma unroll
    for (int cy = 0; cy < 2; cy++)
      #pragma unroll
      for (int cx = 0; cx < 2; cx++) {
        int ix = xs[cx], iy = ys[cy];
        if (ix >= 0 && ix < 32 && iy >= 0 && iy < 32)
          atomicAdd(&lAw[iy * 32 + ix], wxs[cx] * wys[cy]);
      }
  }
  unsigned long long ball = __ballot(valid);
  if ((t & 63) == 0) atomicAdd(&lcnt, (int)__popcll(ball));
  __syncthreads();
  float tsum = 0.f;
  for (int i = t; i < NLOC; i += 256) {
    float v = lAw[i];
    tsum += v;
    if (v != 0.f) atomicAdd(&Aw[b * NLOC + i], v);
  }
  #pragma unroll
  for (int m = 1; m <= 32; m <<= 1) tsum += __shfl_xor(tsum, m, 64);
  if ((t & 63) == 0) wsum[t >> 6] = tsum;
  __syncthreads();
  if (t == 0) {
    float bs = wsum[0] + wsum[1] + wsum[2] + wsum[3];
    if (bs != 0.f) atomicAdd(&sumAw[b], bs);
    if (lcnt) atomicAdd(&cnt[b], (float)lcnt);
  }
}

// ---- merged: compaction (blocks 0..7) + im2col (blocks 8..519) ----
__global__ __launch_bounds__(256) void k_cim(const float* __restrict__ Aw,
                                             int* __restrict__ idxc,
                                             float* __restrict__ Awc,
                                             const float* __restrict__ images,
                                             const float* __restrict__ masks,
                                             short* __restrict__ A1g) {
  __shared__ float S[28 * 452];
  int t = threadIdx.x;
  if (blockIdx.x < NB) {
    int* cnts = (int*)S;
    int* offs = cnts + 256;
    int b = blockIdx.x;
    int base = b * 1024 + t * 4;
    float w[4];
    int c = 0;
    #pragma unroll
    for (int j = 0; j < 4; j++) { w[j] = Aw[base + j]; c += (w[j] != 0.f) ? 1 : 0; }
    cnts[t] = c;
    offs[t] = c;
    __syncthreads();
    for (int s = 1; s < 256; s <<= 1) {
      int v = (t >= s) ? offs[t - s] : 0;
      __syncthreads();
      offs[t] += v;
      __syncthreads();
    }
    int pos = b * CAP + offs[t] - cnts[t];
    int lim = (b + 1) * CAP;
    #pragma unroll
    for (int j = 0; j < 4; j++)
      if (w[j] != 0.f && pos < lim) { idxc[pos] = base + j; Awc[pos] = w[j]; pos++; }
    int total = offs[255];
    for (int i = total + t; i < CAP; i += 256) {
      idxc[b * CAP + i] = b * 1024;
      Awc[b * CAP + i] = 0.f;
    }
    return;
  }
  int bid = blockIdx.x - NB;
  int b = bid >> 6, y = bid & 63;
  int y7 = y * 7;
  for (int p = t; p < 3136; p += 256) {
    int row = p / 112, c4 = p - row * 112;
    int c = row / 7, r = row - c * 7;
    const float* src = (c < 3)
        ? &images[((size_t)(b * 3 + c) * 448 + y7 + r) * 448 + c4 * 4]
        : &masks[((size_t)b * 448 + y7 + r) * 448 + c4 * 4];
    *(float4*)&S[row * 452 + c4 * 4] = *(const float4*)src;
  }
  __syncthreads();
  size_t obase = (size_t)bid * 64 * K1;
  #pragma unroll
  for (int it = 0; it < 7; it++) {
    int p = it * 256 + t;
    int x = p / 28, k16 = p - x * 28;
    const float* s = &S[k16 * 452 + x * 7];
    short o[8];
    #pragma unroll
    for (int j = 0; j < 7; j++) o[j] = f2bf(s[j]);
    o[7] = 0;
    *(bf16x8*)&A1g[obase + (size_t)p * 8] = *(bf16x8*)o;
  }
}

// ---- 64x64-tile bf16 BT GEMM (conv1c, gathered A rows) ----
template<int KDIM, int LDC, int MODE>
__global__ __launch_bounds__(256) void k_gemm64(
    const short* __restrict__ Amat, const int* __restrict__ idxc,
    const short* __restrict__ Bmat, const float* __restrict__ bias,
    short* __restrict__ Cout) {
  __shared__ __align__(16) char Lraw[16384];
  int t = threadIdx.x, lane = t & 63, wv = t >> 6;
  int mt0 = blockIdx.x * 64;
  int nt0 = blockIdx.y * 64;
  f32x4 acc[2][2];
  #pragma unroll
  for (int i = 0; i < 2; i++)
    #pragma unroll
    for (int j = 0; j < 2; j++) acc[i][j] = (f32x4){0.f, 0.f, 0.f, 0.f};

  int srow = lane >> 2, scol = (lane & 3) * 8;
  int wm = wv >> 1, wn = wv & 1;
  int l15 = lane & 15, lg = lane >> 4;

  int arow = mt0 + wv * 16 + srow;
  const short* Ap;
  if (MODE == 1) {
    int i = arow >> 2, pos = arow & 3;
    int loc = idxc[i];
    int b = loc >> 10, oy = (loc >> 5) & 31, ox = loc & 31;
    int yy = oy * 2 + (pos >> 1), xx = ox * 2 + (pos & 1);
    Ap = Amat + (size_t)((b * 64 + yy) * 64 + xx) * KDIM;
  } else {
    Ap = Amat + (size_t)arow * KDIM;
  }
  const short* Bp = Bmat + (size_t)(nt0 + wv * 16 + srow) * KDIM;

  auto STAGE = [&](int buf, int kt) {
    int k0 = kt * 32;
    char* As = Lraw + buf * 8192;
    char* Bs = As + 4096;
    gload_lds16(Ap + k0 + scol, As + wv * 1024);
    gload_lds16(Bp + k0 + scol, Bs + wv * 1024);
  };

  const int NT = KDIM / 32;
  STAGE(0, 0);
  __syncthreads();
  int cur = 0;
  #pragma unroll 2
  for (int kt = 0; kt < NT; kt++) {
    if (kt + 1 < NT) STAGE(cur ^ 1, kt + 1);
    const short* As = (const short*)(Lraw + cur * 8192);
    const short* Bs = As + 2048;
    bf16x8 af[2], bfr[2];
    #pragma unroll
    for (int i = 0; i < 2; i++)
      af[i] = *(const bf16x8*)&As[(wm * 32 + i * 16 + l15) * 32 + lg * 8];
    #pragma unroll
    for (int j = 0; j < 2; j++)
      bfr[j] = *(const bf16x8*)&Bs[(wn * 32 + j * 16 + l15) * 32 + lg * 8];
    #pragma unroll
    for (int i = 0; i < 2; i++)
      #pragma unroll
      for (int j = 0; j < 2; j++)
        acc[i][j] = __builtin_amdgcn_mfma_f32_16x16x32_bf16(af[i], bfr[j], acc[i][j], 0, 0, 0);
    __syncthreads();
    cur ^= 1;
  }

  short* ct = (short*)Lraw;
  #pragma unroll
  for (int i = 0; i < 2; i++)
    #pragma unroll
    for (int j = 0; j < 2; j++) {
      int cl = wn * 32 + j * 16 + l15;
      float bv = bias[nt0 + cl];
      #pragma unroll
      for (int reg = 0; reg < 4; reg++) {
        int rl = wm * 32 + i * 16 + lg * 4 + reg;
        ct[rl * 68 + cl] = f2bf(acc[i][j][reg] + bv);
      }
    }
  __syncthreads();
  #pragma unroll
  for (int it = 0; it < 2; it++) {
    int p = it * 256 + t;
    int row = p >> 3, cc = (p & 7) * 8;
    bf16x8 v = *(const bf16x8*)&ct[row * 68 + cc];
    *(bf16x8*)&Cout[(size_t)(mt0 + row) * LDC + nt0 + cc] = v;
  }
}

// ---- conv2c: 128x64 tile, K-SPLIT via blockIdx.z (2 halves of 512) ----
// grid (24,16,2) = 768 blocks = 3/CU. f32 partial outputs y2p[z] (L3-resident).
__global__ __launch_bounds__(256) void k_gemm2s(
    const short* __restrict__ Amat, const short* __restrict__ Bmat,
    const float* __restrict__ bias, float* __restrict__ y2p0,
    float* __restrict__ y2p1) {
  const int KDIM = 1024;
  __shared__ __align__(16) char Lraw[24576];
  int t = threadIdx.x, lane = t & 63, wv = t >> 6;
  int mt0 = blockIdx.x * 128;
  int nt0 = blockIdx.y * 64;
  int kz = blockIdx.z;
  int kbase = kz * 512;
  float* outp = kz ? y2p1 : y2p0;
  f32x4 acc[4][2];
  #pragma unroll
  for (int i = 0; i < 4; i++)
    #pragma unroll
    for (int j = 0; j < 2; j++) acc[i][j] = (f32x4){0.f, 0.f, 0.f, 0.f};

  int srow = lane >> 2, scol = (lane & 3) * 8;
  int wm = wv >> 1, wn = wv & 1;
  int l15 = lane & 15, lg = lane >> 4;
  int r0 = wv * 16, r1 = 64 + wv * 16;

  auto STAGE = [&](int buf, int kt) {
    int k0 = kbase + kt * 32;
    char* As = Lraw + buf * 12288;
    char* Bs = As + 8192;
    gload_lds16(&Amat[(size_t)(mt0 + r0 + srow) * KDIM + k0 + scol], As + r0 * 64);
    gload_lds16(&Amat[(size_t)(mt0 + r1 + srow) * KDIM + k0 + scol], As + r1 * 64);
    gload_lds16(&Bmat[(size_t)(nt0 + r0 + srow) * KDIM + k0 + scol], Bs + r0 * 64);
  };

  STAGE(0, 0);
  __syncthreads();
  int cur = 0;
  #pragma unroll 2
  for (int kt = 0; kt < 16; kt++) {
    if (kt + 1 < 16) STAGE(cur ^ 1, kt + 1);
    const short* As = (const short*)(Lraw + cur * 12288);
    const short* Bs = As + 4096;
    bf16x8 af[4], bfr[2];
    #pragma unroll
    for (int i = 0; i < 4; i++)
      af[i] = *(const bf16x8*)&As[(wm * 64 + i * 16 + l15) * 32 + lg * 8];
    #pragma unroll
    for (int j = 0; j < 2; j++)
      bfr[j] = *(const bf16x8*)&Bs[(wn * 32 + j * 16 + l15) * 32 + lg * 8];
    #pragma unroll
    for (int i = 0; i < 4; i++)
      #pragma unroll
      for (int j = 0; j < 2; j++)
        acc[i][j] = __builtin_amdgcn_mfma_f32_16x16x32_bf16(af[i], bfr[j], acc[i][j], 0, 0, 0);
    __syncthreads();
    cur ^= 1;
  }

  #pragma unroll
  for (int i = 0; i < 4; i++)
    #pragma unroll
    for (int j = 0; j < 2; j++) {
      int colg = nt0 + wn * 32 + j * 16 + l15;
      float bv = kz ? 0.0f : bias[colg];
      #pragma unroll
      for (int reg = 0; reg < 4; reg++) {
        int rowg = mt0 + wm * 64 + i * 16 + lg * 4 + reg;
        outp[(size_t)rowg * 1024 + colg] = acc[i][j][reg] + bv;
      }
    }
}

// ---- LN(256)+GELU on compacted conv1 rows (linear layout) ----
__global__ __launch_bounds__(256) void k_ln1c(const short* __restrict__ y1c,
                                              const float* __restrict__ ln1w,
                                              const float* __restrict__ ln1b,
                                              short* __restrict__ act1c) {
  int t = threadIdx.x, wv = t >> 6, lane = t & 63;
  int c = lane * 4;
  float lw[4], lb[4];
  #pragma unroll
  for (int j = 0; j < 4; j++) { lw[j] = ln1w[c + j]; lb[j] = ln1b[c + j]; }
  int j0 = blockIdx.x * 64 + wv * 16;
  for (int r = 0; r < 16; r++) {
    int j = j0 + r;
    short4 v4 = *(const short4*)&y1c[(size_t)j * 256 + c];
    float xs[4] = {bf2f(v4.x), bf2f(v4.y), bf2f(v4.z), bf2f(v4.w)};
    float s = 0.f, q = 0.f;
    #pragma unroll
    for (int jj = 0; jj < 4; jj++) { s += xs[jj]; q += xs[jj] * xs[jj]; }
    #pragma unroll
    for (int mm = 1; mm <= 32; mm <<= 1) { s += __shfl_xor(s, mm, 64); q += __shfl_xor(q, mm, 64); }
    float u = s * (1.0f / 256.0f);
    float rs = rsqrtf(q * (1.0f / 256.0f) - u * u + 1e-6f);
    short o[4];
    #pragma unroll
    for (int jj = 0; jj < 4; jj++) o[jj] = f2bf(gelu_f(lw[jj] * ((xs[jj] - u) * rs) + lb[jj]));
    *(short4*)&act1c[(size_t)j * 256 + c] = make_short4(o[0], o[1], o[2], o[3]);
  }
}

// ---- merged LN(1024)+GELU+pool over y2p halves AND gathered-feat pool ----
__global__ __launch_bounds__(256) void k_poolboth(
    const float* __restrict__ y2p0, const float* __restrict__ y2p1,
    const float* __restrict__ feat, const int* __restrict__ idxc,
    const float* __restrict__ ln2w, const float* __restrict__ ln2b,
    const float* __restrict__ Awc, float* __restrict__ partials,
    float* __restrict__ partialsF) {
  int t = threadIdx.x, wv = t >> 6, lane = t & 63;
  int b = blockIdx.x / 12, chunk = blockIdx.x % 12;
  int base = b * CAP + chunk * 32;
  int c0 = lane * 16;
  float lw[16], lb[16], wacc[16], facc[16];
  #pragma unroll
  for (int j = 0; j < 16; j++) {
    lw[j] = ln2w[c0 + j];
    lb[j] = ln2b[c0 + j];
    wacc[j] = 0.f;
    facc[j] = 0.f;
  }
  for (int pass = 0; pass < 8; pass++) {
    int row = base + pass * 4 + wv;
    float wt = Awc[row];
    if (wt == 0.f) continue;
    const float4* fp = (const float4*)(feat + (size_t)idxc[row] * 1024 + c0);
    #pragma unroll
    for (int j = 0; j < 4; j++) {
      float4 v = fp[j];
      facc[j * 4 + 0] += wt * v.x;
      facc[j * 4 + 1] += wt * v.y;
      facc[j * 4 + 2] += wt * v.z;
      facc[j * 4 + 3] += wt * v.w;
    }
    const float4* a0 = (const float4*)(y2p0 + (size_t)row * 1024 + c0);
    const float4* a1 = (const float4*)(y2p1 + (size_t)row * 1024 + c0);
    float xs[16];
    #pragma unroll
    for (int j = 0; j < 4; j++) {
      float4 va = a0[j], vb = a1[j];
      xs[j * 4 + 0] = va.x + vb.x;
      xs[j * 4 + 1] = va.y + vb.y;
      xs[j * 4 + 2] = va.z + vb.z;
      xs[j * 4 + 3] = va.w + vb.w;
    }
    float s = 0.f, q = 0.f;
    #pragma unroll
    for (int j = 0; j < 16; j++) { s += xs[j]; q += xs[j] * xs[j]; }
    #pragma unroll
    for (int m = 1; m <= 32; m <<= 1) { s += __shfl_xor(s, m, 64); q += __shfl_xor(q, m, 64); }
    float u = s * (1.0f / 1024.0f);
    float rs = rsqrtf(q * (1.0f / 1024.0f) - u * u + 1e-6f);
    #pragma unroll
    for (int j = 0; j < 16; j++)
      wacc[j] += wt * gelu_f(lw[j] * ((xs[j] - u) * rs) + lb[j]);
  }
  float* dst = &partials[((size_t)blockIdx.x * 4 + wv) * 1024 + c0];
  float* dstF = &partialsF[((size_t)blockIdx.x * 4 + wv) * 1024 + c0];
  #pragma unroll
  for (int j = 0; j < 4; j++) {
    *(f32x4*)&dst[j * 4] = (f32x4){wacc[j * 4], wacc[j * 4 + 1], wacc[j * 4 + 2], wacc[j * 4 + 3]};
    *(f32x4*)&dstF[j * 4] = (f32x4){facc[j * 4], facc[j * 4 + 1], facc[j * 4 + 2], facc[j * 4 + 3]};
  }
}

// ---- reduce both partial arrays: 48 slots per batch each ----
__global__ __launch_bounds__(256) void k_red(const float* __restrict__ partials,
                                             const float* __restrict__ partialsF,
                                             float* __restrict__ pa,
                                             float* __restrict__ pf) {
  int c = blockIdx.x * 256 + threadIdx.x;
  int b = c >> 10, ch = c & 1023;
  const float* p = partials + (size_t)(b * 48) * 1024 + ch;
  const float* pF = partialsF + (size_t)(b * 48) * 1024 + ch;
  float s = 0.f, sf = 0.f;
  #pragma unroll 8
  for (int j = 0; j < 48; j++) {
    s += p[(size_t)j * 1024];
    sf += pF[(size_t)j * 1024];
  }
  pa[c] = s;
  pf[c] = sf;
}

// ---- conv3 folded past the pool: wave-per-channel, c3w read once ----
__global__ __launch_bounds__(256) void k_mix(const float* __restrict__ pa,
                                             const float* __restrict__ pf,
                                             const float* __restrict__ sumAw,
                                             const float* __restrict__ cnt,
                                             const float* __restrict__ c3w,
                                             const float* __restrict__ c3b,
                                             float* __restrict__ zn) {
  __shared__ float pl[8192];
  int t = threadIdx.x;
  for (int idx = t; idx < 2048; idx += 256)
    ((float4*)pl)[idx] = ((const float4*)pa)[idx];
  __syncthreads();
  int wv = t >> 6, lane = t & 63;
  int c = blockIdx.x * 4 + wv;
  float w[16];
  #pragma unroll
  for (int i = 0; i < 16; i++) w[i] = c3w[(size_t)c * 1024 + i * 64 + lane];
  float s[8];
  #pragma unroll
  for (int b = 0; b < 8; b++) s[b] = 0.f;
  #pragma unroll
  for (int i = 0; i < 16; i++) {
    int k = i * 64 + lane;
    #pragma unroll
    for (int b = 0; b < 8; b++) s[b] += w[i] * pl[b * 1024 + k];
  }
  #pragma unroll
  for (int m = 1; m <= 32; m <<= 1)
    #pragma unroll
    for (int b = 0; b < 8; b++) s[b] += __shfl_xor(s[b], m, 64);
  if (lane < 8) {
    float cv = cnt[lane];
    float z = s[lane] + sumAw[lane] * c3b[c] + pf[lane * 1024 + c];
    zn[lane * 1024 + c] = cv > 0.f ? z / cv : 0.f;
  }
}

// ---- final GEMV: 1024 blocks, one wave per output row, 8 batches/wave ----
__global__ __launch_bounds__(256) void k_out(const float* __restrict__ zn,
                                             const float* __restrict__ up_w,
                                             const float* __restrict__ up_b,
                                             float* __restrict__ out) {
  __shared__ float pl[8192];
  int t = threadIdx.x;
  for (int idx = t; idx < 2048; idx += 256)
    ((float4*)pl)[idx] = ((const float4*)zn)[idx];
  __syncthreads();
  int wv = t >> 6, lane = t & 63;
  int o = blockIdx.x * 4 + wv;
  float w[16];
  #pragma unroll
  for (int i = 0; i < 16; i++) w[i] = up_w[(size_t)o * 1024 + i * 64 + lane];
  float s[8];
  #pragma unroll
  for (int b = 0; b < 8; b++) s[b] = 0.f;
  #pragma unroll
  for (int i = 0; i < 16; i++) {
    int k = i * 64 + lane;
    #pragma unroll
    for (int b = 0; b < 8; b++) s[b] += w[i] * pl[b * 1024 + k];
  }
  #pragma unroll
  for (int m = 1; m <= 32; m <<= 1)
    #pragma unroll
    for (int b = 0; b < 8; b++) s[b] += __shfl_xor(s[b], m, 64);
  if (lane < 8) out[(size_t)lane * NOUT + o] = s[lane] + up_b[o];
}

extern "C" void kernel_launch(void* const* d_in, const int* in_sizes, int n_in,
                              void* d_out, int out_size, void* d_ws, size_t ws_size,
                              hipStream_t stream) {
  const float* images = (const float*)d_in[0];
  const float* masks  = (const float*)d_in[1];
  const float* feat   = (const float*)d_in[2];
  const float* coords = (const float*)d_in[3];
  const float* c1w  = (const float*)d_in[5];
  const float* c1b  = (const float*)d_in[6];
  const float* ln1w = (const float*)d_in[7];
  const float* ln1b = (const float*)d_in[8];
  const float* c2w  = (const float*)d_in[9];
  const float* c2b  = (const float*)d_in[10];
  const float* ln2w = (const float*)d_in[11];
  const float* ln2b = (const float*)d_in[12];
  const float* c3w  = (const float*)d_in[13];
  const float* c3b  = (const float*)d_in[14];
  const float* up_w = (const float*)d_in[15];
  const float* up_b = (const float*)d_in[16];
  float* out = (float*)d_out;

  char* ws = (char*)d_ws;
  size_t off = 0;
  auto alloc = [&](size_t bytes) -> void* {
    void* p = ws + off;
    off = (off + bytes + 255) & ~(size_t)255;
    return p;
  };
  float* Aw    = (float*)alloc(8192 * 4);
  float* cnt   = (float*)alloc(8 * 4);
  float* sumAw = (float*)alloc(8 * 4);
  size_t zeroBytes = off;
  int*   idxc  = (int*)alloc(MC * 4);
  float* Awc   = (float*)alloc(MC * 4);
  float* pa    = (float*)alloc(8192 * 4);
  float* pf    = (float*)alloc(8192 * 4);
  float* partials  = (float*)alloc((size_t)384 * 1024 * 4);
  float* partialsF = (float*)alloc((size_t)384 * 1024 * 4);
  float* zn   = (float*)alloc(8192 * 4);
  short* c1wb = (short*)alloc((size_t)CH1 * K1 * 2);
  short* w2p  = (short*)alloc((size_t)CH2 * CH2 * 2);
  short* A1g  = (short*)alloc((size_t)M1 * K1 * 2);
  short* y1c  = (short*)alloc((size_t)M1C * 256 * 2);
  short* act1c = (short*)alloc((size_t)MC * 1024 * 2);
  float* y2p0 = (float*)alloc((size_t)MC * 1024 * 4);
  float* y2p1 = (float*)alloc((size_t)MC * 1024 * 4);

  int n4 = (int)(zeroBytes / 16);
  k_prep<<<4096, 256, 0, stream>>>(c1w, c2w, c1wb, w2p, (float4*)d_ws, n4);
  k_pts<<<NB * 49, 256, 0, stream>>>(coords, Aw, cnt, sumAw);
  k_cim<<<NB + 512, 256, 0, stream>>>(Aw, idxc, Awc, images, masks, A1g);
  k_gemm64<K1, 256, 1><<<dim3(M1C / 64, 4), 256, 0, stream>>>(A1g, idxc, c1wb, c1b, y1c);
  k_ln1c<<<M1C / 64, 256, 0, stream>>>(y1c, ln1w, ln1b, act1c);
  k_gemm2s<<<dim3(MC / 128, 16, 2), 256, 0, stream>>>(act1c, w2p, c2b, y2p0, y2p1);
  k_poolboth<<<96, 256, 0, stream>>>(y2p0, y2p1, feat, idxc, ln2w, ln2b, Awc, partials, partialsF);
  k_red<<<32, 256, 0, stream>>>(partials, partialsF, pa, pf);
  k_mix<<<256, 256, 0, stream>>>(pa, pf, sumAw, cnt, c3w, c3b, zn);
  k_out<<<NOUT / 4, 256, 0, stream>>>(zn, up_w, up_b, out);
}

// Round 17
// 110.280 us; speedup vs baseline: 1.7636x; 1.0078x over previous
//
#include <hip/hip_runtime.h>
#include <stdint.h>

// Problem constants
#define NB 8
#define HIN 448
#define CH1 256
#define CH2 1024
#define NLOC 1024        // 32*32
#define M2 8192          // NB*NLOC
#define M1 32768         // NB*64*64 conv1 output locations
#define K1 224           // padded im2col K: c*56 + r*8 + cc(0..7), cc==7 -> 0
#define NPTS 12544
#define NOUT 4096
#define CAP 384          // per-batch compacted-row capacity (>= 18*18=324 bound)
#define MC (NB * CAP)    // 3072 compacted conv2 rows
#define M1C (MC * 4)     // 12288 compacted conv1 rows

typedef __attribute__((ext_vector_type(8))) short bf16x8;
typedef __attribute__((ext_vector_type(4))) float f32x4;

__device__ __forceinline__ short f2bf(float f) {
  uint32_t u = __builtin_bit_cast(uint32_t, f);
  uint32_t r = (u + 0x7fffu + ((u >> 16) & 1u)) >> 16;
  return (short)r;
}
__device__ __forceinline__ float bf2f(short s) {
  return __builtin_bit_cast(float, (uint32_t)(uint16_t)s << 16);
}
__device__ __forceinline__ float gelu_f(float x) {
  return 0.5f * x * (1.0f + erff(x * 0.70710678118654752f));
}
__device__ __forceinline__ void gload_lds16(const void* g, void* l) {
  __builtin_amdgcn_global_load_lds((const __attribute__((address_space(1))) unsigned int*)g,
                                   (__attribute__((address_space(3))) unsigned int*)l, 16, 0, 0);
}

// ---- merged: workspace zero + weight cast/permute ----
__global__ void k_prep(const float* __restrict__ c1w, const float* __restrict__ c2w,
                       short* __restrict__ c1wb, short* __restrict__ w2p,
                       float4* __restrict__ zp, int n4) {
  int i = blockIdx.x * 256 + threadIdx.x;
  if (i < n4) zp[i] = make_float4(0.f, 0.f, 0.f, 0.f);
  if (i < CH1 * K1) {
    int o = i / K1, k = i - o * K1;
    int c = k / 56, kk = k - c * 56, r = kk >> 3, cc = kk & 7;
    c1wb[i] = f2bf(cc < 7 ? c1w[((o * 4 + c) * 7 + r) * 7 + cc] : 0.0f);
  }
  if (i < CH2 * CH2) {
    int o = i >> 10, k = i & 1023;
    int pos = k >> 8, ci = k & 255;
    w2p[i] = f2bf(c2w[(size_t)(o * 256 + ci) * 4 + pos]);
  }
}

// ---- point -> bilinear weight accumulation (LDS-aggregated, G12) ----
__global__ __launch_bounds__(256) void k_pts(const float* __restrict__ coords,
                                             float* __restrict__ Aw,
                                             float* __restrict__ cnt,
                                             float* __restrict__ sumAw) {
  __shared__ float lAw[NLOC];
  __shared__ int lcnt;
  __shared__ float wsum[4];
  int t = threadIdx.x;
  int b = blockIdx.x / 49;
  int blk = blockIdx.x - b * 49;
  for (int i = t; i < NLOC; i += 256) lAw[i] = 0.f;
  if (t == 0) lcnt = 0;
  __syncthreads();
  int pi = blk * 256 + t;
  float x = coords[((size_t)b * NPTS + pi) * 2];
  float y = coords[((size_t)b * NPTS + pi) * 2 + 1];
  bool valid = (x >= 0.0f);
  if (valid) {
    float gx = x * 32.0f - 0.5f, gy = y * 32.0f - 0.5f;
    float x0f = floorf(gx), y0f = floorf(gy);
    int x0 = (int)x0f, y0 = (int)y0f;
    float wx1 = gx - x0f, wx0 = 1.0f - wx1;
    float wy1 = gy - y0f, wy0 = 1.0f - wy1;
    int xs[2] = {x0, x0 + 1}, ys[2] = {y0, y0 + 1};
    float wxs[2] = {wx0, wx1}, wys[2] = {wy0, wy1};
    #pragma unroll
    for (int cy = 0; cy < 2; cy++)
      #pragma unroll
      for (int cx = 0; cx < 2; cx++) {
        int ix = xs[cx], iy = ys[cy];
        if (ix >= 0 && ix < 32 && iy >= 0 && iy < 32)
          atomicAdd(&lAw[iy * 32 + ix], wxs[cx] * wys[cy]);
      }
  }
  unsigned long long ball = __ballot(valid);
  if ((t & 63) == 0) atomicAdd(&lcnt, (int)__popcll(ball));
  __syncthreads();
  float tsum = 0.f;
  for (int i = t; i < NLOC; i += 256) {
    float v = lAw[i];
    tsum += v;
    if (v != 0.f) atomicAdd(&Aw[b * NLOC + i], v);
  }
  #pragma unroll
  for (int m = 1; m <= 32; m <<= 1) tsum += __shfl_xor(tsum, m, 64);
  if ((t & 63) == 0) wsum[t >> 6] = tsum;
  __syncthreads();
  if (t == 0) {
    float bs = wsum[0] + wsum[1] + wsum[2] + wsum[3];
    if (bs != 0.f) atomicAdd(&sumAw[b], bs);
    if (lcnt) atomicAdd(&cnt[b], (float)lcnt);
  }
}

// ---- per-batch ordered prefix-scan compaction (8 blocks) ----
__global__ __launch_bounds__(256) void k_compact(const float* __restrict__ Aw,
                                                 int* __restrict__ idxc,
                                                 float* __restrict__ Awc) {
  __shared__ int cnts[256], offs[256];
  int t = threadIdx.x, b = blockIdx.x;
  int base = b * 1024 + t * 4;
  float w[4];
  int c = 0;
  #pragma unroll
  for (int j = 0; j < 4; j++) { w[j] = Aw[base + j]; c += (w[j] != 0.f) ? 1 : 0; }
  cnts[t] = c;
  offs[t] = c;
  __syncthreads();
  for (int s = 1; s < 256; s <<= 1) {
    int v = (t >= s) ? offs[t - s] : 0;
    __syncthreads();
    offs[t] += v;
    __syncthreads();
  }
  int pos = b * CAP + offs[t] - cnts[t];
  int lim = (b + 1) * CAP;
  #pragma unroll
  for (int j = 0; j < 4; j++)
    if (w[j] != 0.f && pos < lim) { idxc[pos] = base + j; Awc[pos] = w[j]; pos++; }
  int total = offs[255];
  for (int i = total + t; i < CAP; i += 256) {
    idxc[b * CAP + i] = b * 1024;
    Awc[b * CAP + i] = 0.f;
  }
}

// ---- gathered im2col: only the 12288 active conv1 rows ----
// Block = 16 compacted locs (64 A1c rows). Thread = (loc, c, kh, rhalf).
// Reads each active loc's 14x14 patch per channel as aligned float2 runs.
// A1c[j][224], j = i*4 + kh*2 + kw, k-layout = c*56 + r*8 + cc (cc==7 -> 0).
__global__ __launch_bounds__(256) void k_imc(const int* __restrict__ idxc,
                                             const float* __restrict__ images,
                                             const float* __restrict__ masks,
                                             short* __restrict__ A1c) {
  __shared__ short ct[64 * K1];   // 28K
  int t = threadIdx.x;
  int i0 = blockIdx.x * 16;
  int loc = t >> 4;
  int rem = t & 15;
  int c = rem >> 2, kh = (rem >> 1) & 1, rh = rem & 1;
  int gi = idxc[i0 + loc];
  int b = gi >> 10, oy = (gi >> 5) & 31, ox = gi & 31;
  int yy = oy * 2 + kh;
  int xbase = ox * 14;            // even*7 -> 8B-aligned float2 runs
  int r0 = rh * 4, rn = rh ? 3 : 4;
  const float* plane = (c < 3)
      ? images + (size_t)(b * 3 + c) * 448 * 448
      : masks + (size_t)b * 448 * 448;
  for (int rr = 0; rr < rn; rr++) {
    int r = r0 + rr;
    const float* src = plane + (size_t)(yy * 7 + r) * 448 + xbase;
    short tmp[14];
    #pragma unroll
    for (int p = 0; p < 7; p++) {
      float2 v = *(const float2*)&src[p * 2];
      tmp[p * 2] = f2bf(v.x);
      tmp[p * 2 + 1] = f2bf(v.y);
    }
    #pragma unroll
    for (int kw = 0; kw < 2; kw++) {
      short* dst = &ct[(loc * 4 + kh * 2 + kw) * K1 + c * 56 + r * 8];
      #pragma unroll
      for (int cc = 0; cc < 7; cc++) dst[cc] = tmp[kw * 7 + cc];
      dst[7] = 0;
    }
  }
  __syncthreads();
  size_t obase = (size_t)blockIdx.x * 64 * K1;
  #pragma unroll
  for (int it = 0; it < 7; it++) {
    int p = it * 256 + t;           // 1792 16B chunks
    *(bf16x8*)&A1c[obase + (size_t)p * 8] = *(const bf16x8*)&ct[p * 8];
  }
}

// ---- 64x64-tile bf16 BT GEMM (conv1c, linear A) ----
template<int KDIM, int LDC>
__global__ __launch_bounds__(256) void k_gemm64(
    const short* __restrict__ Amat, const short* __restrict__ Bmat,
    const float* __restrict__ bias, short* __restrict__ Cout) {
  __shared__ __align__(16) char Lraw[16384];
  int t = threadIdx.x, lane = t & 63, wv = t >> 6;
  int mt0 = blockIdx.x * 64;
  int nt0 = blockIdx.y * 64;
  f32x4 acc[2][2];
  #pragma unroll
  for (int i = 0; i < 2; i++)
    #pragma unroll
    for (int j = 0; j < 2; j++) acc[i][j] = (f32x4){0.f, 0.f, 0.f, 0.f};

  int srow = lane >> 2, scol = (lane & 3) * 8;
  int wm = wv >> 1, wn = wv & 1;
  int l15 = lane & 15, lg = lane >> 4;

  const short* Ap = Amat + (size_t)(mt0 + wv * 16 + srow) * KDIM;
  const short* Bp = Bmat + (size_t)(nt0 + wv * 16 + srow) * KDIM;

  auto STAGE = [&](int buf, int kt) {
    int k0 = kt * 32;
    char* As = Lraw + buf * 8192;
    char* Bs = As + 4096;
    gload_lds16(Ap + k0 + scol, As + wv * 1024);
    gload_lds16(Bp + k0 + scol, Bs + wv * 1024);
  };

  const int NT = KDIM / 32;
  STAGE(0, 0);
  __syncthreads();
  int cur = 0;
  #pragma unroll 2
  for (int kt = 0; kt < NT; kt++) {
    if (kt + 1 < NT) STAGE(cur ^ 1, kt + 1);
    const short* As = (const short*)(Lraw + cur * 8192);
    const short* Bs = As + 2048;
    bf16x8 af[2], bfr[2];
    #pragma unroll
    for (int i = 0; i < 2; i++)
      af[i] = *(const bf16x8*)&As[(wm * 32 + i * 16 + l15) * 32 + lg * 8];
    #pragma unroll
    for (int j = 0; j < 2; j++)
      bfr[j] = *(const bf16x8*)&Bs[(wn * 32 + j * 16 + l15) * 32 + lg * 8];
    #pragma unroll
    for (int i = 0; i < 2; i++)
      #pragma unroll
      for (int j = 0; j < 2; j++)
        acc[i][j] = __builtin_amdgcn_mfma_f32_16x16x32_bf16(af[i], bfr[j], acc[i][j], 0, 0, 0);
    __syncthreads();
    cur ^= 1;
  }

  short* ct = (short*)Lraw;
  #pragma unroll
  for (int i = 0; i < 2; i++)
    #pragma unroll
    for (int j = 0; j < 2; j++) {
      int cl = wn * 32 + j * 16 + l15;
      float bv = bias[nt0 + cl];
      #pragma unroll
      for (int reg = 0; reg < 4; reg++) {
        int rl = wm * 32 + i * 16 + lg * 4 + reg;
        ct[rl * 68 + cl] = f2bf(acc[i][j][reg] + bv);
      }
    }
  __syncthreads();
  #pragma unroll
  for (int it = 0; it < 2; it++) {
    int p = it * 256 + t;
    int row = p >> 3, cc = (p & 7) * 8;
    bf16x8 v = *(const bf16x8*)&ct[row * 68 + cc];
    *(bf16x8*)&Cout[(size_t)(mt0 + row) * LDC + nt0 + cc] = v;
  }
}

// ---- conv2c: 128x64 tile, K-split + XCD swizzle (768 blocks, 1D grid) ----
__global__ __launch_bounds__(256) void k_gemm2s(
    const short* __restrict__ Amat, const short* __restrict__ Bmat,
    const float* __restrict__ bias, float* __restrict__ y2p0,
    float* __restrict__ y2p1) {
  const int KDIM = 1024;
  __shared__ __align__(16) char Lraw[24576];
  int t = threadIdx.x, lane = t & 63, wv = t >> 6;
  // XCD swizzle: 768 % 8 == 0, each XCD gets 96 consecutive work items
  int swz = (blockIdx.x & 7) * 96 + (blockIdx.x >> 3);
  int kz = swz / 384;
  int rem = swz - kz * 384;
  int by = rem / 24;
  int bx = rem - by * 24;
  int mt0 = bx * 128;
  int nt0 = by * 64;
  int kbase = kz * 512;
  float* outp = kz ? y2p1 : y2p0;
  f32x4 acc[4][2];
  #pragma unroll
  for (int i = 0; i < 4; i++)
    #pragma unroll
    for (int j = 0; j < 2; j++) acc[i][j] = (f32x4){0.f, 0.f, 0.f, 0.f};

  int srow = lane >> 2, scol = (lane & 3) * 8;
  int wm = wv >> 1, wn = wv & 1;
  int l15 = lane & 15, lg = lane >> 4;
  int r0 = wv * 16, r1 = 64 + wv * 16;

  auto STAGE = [&](int buf, int kt) {
    int k0 = kbase + kt * 32;
    char* As = Lraw + buf * 12288;
    char* Bs = As + 8192;
    gload_lds16(&Amat[(size_t)(mt0 + r0 + srow) * KDIM + k0 + scol], As + r0 * 64);
    gload_lds16(&Amat[(size_t)(mt0 + r1 + srow) * KDIM + k0 + scol], As + r1 * 64);
    gload_lds16(&Bmat[(size_t)(nt0 + r0 + srow) * KDIM + k0 + scol], Bs + r0 * 64);
  };

  STAGE(0, 0);
  __syncthreads();
  int cur = 0;
  #pragma unroll 2
  for (int kt = 0; kt < 16; kt++) {
    if (kt + 1 < 16) STAGE(cur ^ 1, kt + 1);
    const short* As = (const short*)(Lraw + cur * 12288);
    const short* Bs = As + 4096;
    bf16x8 af[4], bfr[2];
    #pragma unroll
    for (int i = 0; i < 4; i++)
      af[i] = *(const bf16x8*)&As[(wm * 64 + i * 16 + l15) * 32 + lg * 8];
    #pragma unroll
    for (int j = 0; j < 2; j++)
      bfr[j] = *(const bf16x8*)&Bs[(wn * 32 + j * 16 + l15) * 32 + lg * 8];
    #pragma unroll
    for (int i = 0; i < 4; i++)
      #pragma unroll
      for (int j = 0; j < 2; j++)
        acc[i][j] = __builtin_amdgcn_mfma_f32_16x16x32_bf16(af[i], bfr[j], acc[i][j], 0, 0, 0);
    __syncthreads();
    cur ^= 1;
  }

  #pragma unroll
  for (int i = 0; i < 4; i++)
    #pragma unroll
    for (int j = 0; j < 2; j++) {
      int colg = nt0 + wn * 32 + j * 16 + l15;
      float bv = kz ? 0.0f : bias[colg];
      #pragma unroll
      for (int reg = 0; reg < 4; reg++) {
        int rowg = mt0 + wm * 64 + i * 16 + lg * 4 + reg;
        outp[(size_t)rowg * 1024 + colg] = acc[i][j][reg] + bv;
      }
    }
}

// ---- LN(256)+GELU on compacted conv1 rows (linear layout) ----
__global__ __launch_bounds__(256) void k_ln1c(const short* __restrict__ y1c,
                                              const float* __restrict__ ln1w,
                                              const float* __restrict__ ln1b,
                                              short* __restrict__ act1c) {
  int t = threadIdx.x, wv = t >> 6, lane = t & 63;
  int c = lane * 4;
  float lw[4], lb[4];
  #pragma unroll
  for (int j = 0; j < 4; j++) { lw[j] = ln1w[c + j]; lb[j] = ln1b[c + j]; }
  int j0 = blockIdx.x * 64 + wv * 16;
  for (int r = 0; r < 16; r++) {
    int j = j0 + r;
    short4 v4 = *(const short4*)&y1c[(size_t)j * 256 + c];
    float xs[4] = {bf2f(v4.x), bf2f(v4.y), bf2f(v4.z), bf2f(v4.w)};
    float s = 0.f, q = 0.f;
    #pragma unroll
    for (int jj = 0; jj < 4; jj++) { s += xs[jj]; q += xs[jj] * xs[jj]; }
    #pragma unroll
    for (int mm = 1; mm <= 32; mm <<= 1) { s += __shfl_xor(s, mm, 64); q += __shfl_xor(q, mm, 64); }
    float u = s * (1.0f / 256.0f);
    float rs = rsqrtf(q * (1.0f / 256.0f) - u * u + 1e-6f);
    short o[4];
    #pragma unroll
    for (int jj = 0; jj < 4; jj++) o[jj] = f2bf(gelu_f(lw[jj] * ((xs[jj] - u) * rs) + lb[jj]));
    *(short4*)&act1c[(size_t)j * 256 + c] = make_short4(o[0], o[1], o[2], o[3]);
  }
}

// ---- merged LN(1024)+GELU+pool over y2p halves AND gathered-feat pool ----
__global__ __launch_bounds__(256) void k_poolboth(
    const float* __restrict__ y2p0, const float* __restrict__ y2p1,
    const float* __restrict__ feat, const int* __restrict__ idxc,
    const float* __restrict__ ln2w, const float* __restrict__ ln2b,
    const float* __restrict__ Awc, float* __restrict__ partials,
    float* __restrict__ partialsF) {
  int t = threadIdx.x, wv = t >> 6, lane = t & 63;
  int b = blockIdx.x / 12, chunk = blockIdx.x % 12;
  int base = b * CAP + chunk * 32;
  int c0 = lane * 16;
  float lw[16], lb[16], wacc[16], facc[16];
  #pragma unroll
  for (int j = 0; j < 16; j++) {
    lw[j] = ln2w[c0 + j];
    lb[j] = ln2b[c0 + j];
    wacc[j] = 0.f;
    facc[j] = 0.f;
  }
  for (int pass = 0; pass < 8; pass++) {
    int row = base + pass * 4 + wv;
    float wt = Awc[row];
    if (wt == 0.f) continue;
    const float4* fp = (const float4*)(feat + (size_t)idxc[row] * 1024 + c0);
    #pragma unroll
    for (int j = 0; j < 4; j++) {
      float4 v = fp[j];
      facc[j * 4 + 0] += wt * v.x;
      facc[j * 4 + 1] += wt * v.y;
      facc[j * 4 + 2] += wt * v.z;
      facc[j * 4 + 3] += wt * v.w;
    }
    const float4* a0 = (const float4*)(y2p0 + (size_t)row * 1024 + c0);
    const float4* a1 = (const float4*)(y2p1 + (size_t)row * 1024 + c0);
    float xs[16];
    #pragma unroll
    for (int j = 0; j < 4; j++) {
      float4 va = a0[j], vb = a1[j];
      xs[j * 4 + 0] = va.x + vb.x;
      xs[j * 4 + 1] = va.y + vb.y;
      xs[j * 4 + 2] = va.z + vb.z;
      xs[j * 4 + 3] = va.w + vb.w;
    }
    float s = 0.f, q = 0.f;
    #pragma unroll
    for (int j = 0; j < 16; j++) { s += xs[j]; q += xs[j] * xs[j]; }
    #pragma unroll
    for (int m = 1; m <= 32; m <<= 1) { s += __shfl_xor(s, m, 64); q += __shfl_xor(q, m, 64); }
    float u = s * (1.0f / 1024.0f);
    float rs = rsqrtf(q * (1.0f / 1024.0f) - u * u + 1e-6f);
    #pragma unroll
    for (int j = 0; j < 16; j++)
      wacc[j] += wt * gelu_f(lw[j] * ((xs[j] - u) * rs) + lb[j]);
  }
  float* dst = &partials[((size_t)blockIdx.x * 4 + wv) * 1024 + c0];
  float* dstF = &partialsF[((size_t)blockIdx.x * 4 + wv) * 1024 + c0];
  #pragma unroll
  for (int j = 0; j < 4; j++) {
    *(f32x4*)&dst[j * 4] = (f32x4){wacc[j * 4], wacc[j * 4 + 1], wacc[j * 4 + 2], wacc[j * 4 + 3]};
    *(f32x4*)&dstF[j * 4] = (f32x4){facc[j * 4], facc[j * 4 + 1], facc[j * 4 + 2], facc[j * 4 + 3]};
  }
}

// ---- reduce both partial arrays: 48 slots per batch each ----
__global__ __launch_bounds__(256) void k_red(const float* __restrict__ partials,
                                             const float* __restrict__ partialsF,
                                             float* __restrict__ pa,
                                             float* __restrict__ pf) {
  int c = blockIdx.x * 256 + threadIdx.x;
  int b = c >> 10, ch = c & 1023;
  const float* p = partials + (size_t)(b * 48) * 1024 + ch;
  const float* pF = partialsF + (size_t)(b * 48) * 1024 + ch;
  float s = 0.f, sf = 0.f;
  #pragma unroll 8
  for (int j = 0; j < 48; j++) {
    s += p[(size_t)j * 1024];
    sf += pF[(size_t)j * 1024];
  }
  pa[c] = s;
  pf[c] = sf;
}

// ---- conv3 folded past the pool: wave-per-channel, c3w read once ----
__global__ __launch_bounds__(256) void k_mix(const float* __restrict__ pa,
                                             const float* __restrict__ pf,
                                             const float* __restrict__ sumAw,
                                             const float* __restrict__ cnt,
                                             const float* __restrict__ c3w,
                                             const float* __restrict__ c3b,
                                             float* __restrict__ zn) {
  __shared__ float pl[8192];
  int t = threadIdx.x;
  for (int idx = t; idx < 2048; idx += 256)
    ((float4*)pl)[idx] = ((const float4*)pa)[idx];
  __syncthreads();
  int wv = t >> 6, lane = t & 63;
  int c = blockIdx.x * 4 + wv;
  float w[16];
  #pragma unroll
  for (int i = 0; i < 16; i++) w[i] = c3w[(size_t)c * 1024 + i * 64 + lane];
  float s[8];
  #pragma unroll
  for (int b = 0; b < 8; b++) s[b] = 0.f;
  #pragma unroll
  for (int i = 0; i < 16; i++) {
    int k = i * 64 + lane;
    #pragma unroll
    for (int b = 0; b < 8; b++) s[b] += w[i] * pl[b * 1024 + k];
  }
  #pragma unroll
  for (int m = 1; m <= 32; m <<= 1)
    #pragma unroll
    for (int b = 0; b < 8; b++) s[b] += __shfl_xor(s[b], m, 64);
  if (lane < 8) {
    float cv = cnt[lane];
    float z = s[lane] + sumAw[lane] * c3b[c] + pf[lane * 1024 + c];
    zn[lane * 1024 + c] = cv > 0.f ? z / cv : 0.f;
  }
}

// ---- final GEMV: 1024 blocks, one wave per output row, 8 batches/wave ----
__global__ __launch_bounds__(256) void k_out(const float* __restrict__ zn,
                                             const float* __restrict__ up_w,
                                             const float* __restrict__ up_b,
                                             float* __restrict__ out) {
  __shared__ float pl[8192];
  int t = threadIdx.x;
  for (int idx = t; idx < 2048; idx += 256)
    ((float4*)pl)[idx] = ((const float4*)zn)[idx];
  __syncthreads();
  int wv = t >> 6, lane = t & 63;
  int o = blockIdx.x * 4 + wv;
  float w[16];
  #pragma unroll
  for (int i = 0; i < 16; i++) w[i] = up_w[(size_t)o * 1024 + i * 64 + lane];
  float s[8];
  #pragma unroll
  for (int b = 0; b < 8; b++) s[b] = 0.f;
  #pragma unroll
  for (int i = 0; i < 16; i++) {
    int k = i * 64 + lane;
    #pragma unroll
    for (int b = 0; b < 8; b++) s[b] += w[i] * pl[b * 1024 + k];
  }
  #pragma unroll
  for (int m = 1; m <= 32; m <<= 1)
    #pragma unroll
    for (int b = 0; b < 8; b++) s[b] += __shfl_xor(s[b], m, 64);
  if (lane < 8) out[(size_t)lane * NOUT + o] = s[lane] + up_b[o];
}

extern "C" void kernel_launch(void* const* d_in, const int* in_sizes, int n_in,
                              void* d_out, int out_size, void* d_ws, size_t ws_size,
                              hipStream_t stream) {
  const float* images = (const float*)d_in[0];
  const float* masks  = (const float*)d_in[1];
  const float* feat   = (const float*)d_in[2];
  const float* coords = (const float*)d_in[3];
  const float* c1w  = (const float*)d_in[5];
  const float* c1b  = (const float*)d_in[6];
  const float* ln1w = (const float*)d_in[7];
  const float* ln1b = (const float*)d_in[8];
  const float* c2w  = (const float*)d_in[9];
  const float* c2b  = (const float*)d_in[10];
  const float* ln2w = (const float*)d_in[11];
  const float* ln2b = (const float*)d_in[12];
  const float* c3w  = (const float*)d_in[13];
  const float* c3b  = (const float*)d_in[14];
  const float* up_w = (const float*)d_in[15];
  const float* up_b = (const float*)d_in[16];
  float* out = (float*)d_out;

  char* ws = (char*)d_ws;
  size_t off = 0;
  auto alloc = [&](size_t bytes) -> void* {
    void* p = ws + off;
    off = (off + bytes + 255) & ~(size_t)255;
    return p;
  };
  float* Aw    = (float*)alloc(8192 * 4);
  float* cnt   = (float*)alloc(8 * 4);
  float* sumAw = (float*)alloc(8 * 4);
  size_t zeroBytes = off;
  int*   idxc  = (int*)alloc(MC * 4);
  float* Awc   = (float*)alloc(MC * 4);
  float* pa    = (float*)alloc(8192 * 4);
  float* pf    = (float*)alloc(8192 * 4);
  float* partials  = (float*)alloc((size_t)384 * 1024 * 4);
  float* partialsF = (float*)alloc((size_t)384 * 1024 * 4);
  float* zn   = (float*)alloc(8192 * 4);
  short* c1wb = (short*)alloc((size_t)CH1 * K1 * 2);
  short* w2p  = (short*)alloc((size_t)CH2 * CH2 * 2);
  short* A1c  = (short*)alloc((size_t)M1C * K1 * 2);
  short* y1c  = (short*)alloc((size_t)M1C * 256 * 2);
  short* act1c = (short*)alloc((size_t)MC * 1024 * 2);
  float* y2p0 = (float*)alloc((size_t)MC * 1024 * 4);
  float* y2p1 = (float*)alloc((size_t)MC * 1024 * 4);

  int n4 = (int)(zeroBytes / 16);
  k_prep<<<4096, 256, 0, stream>>>(c1w, c2w, c1wb, w2p, (float4*)d_ws, n4);
  k_pts<<<NB * 49, 256, 0, stream>>>(coords, Aw, cnt, sumAw);
  k_compact<<<NB, 256, 0, stream>>>(Aw, idxc, Awc);
  k_imc<<<MC / 16, 256, 0, stream>>>(idxc, images, masks, A1c);
  k_gemm64<K1, 256><<<dim3(M1C / 64, 4), 256, 0, stream>>>(A1c, c1wb, c1b, y1c);
  k_ln1c<<<M1C / 64, 256, 0, stream>>>(y1c, ln1w, ln1b, act1c);
  k_gemm2s<<<768, 256, 0, stream>>>(act1c, w2p, c2b, y2p0, y2p1);
  k_poolboth<<<96, 256, 0, stream>>>(y2p0, y2p1, feat, idxc, ln2w, ln2b, Awc, partials, partialsF);
  k_red<<<32, 256, 0, stream>>>(partials, partialsF, pa, pf);
  k_mix<<<256, 256, 0, stream>>>(pa, pf, sumAw, cnt, c3w, c3b, zn);
  k_out<<<NOUT / 4, 256, 0, stream>>>(zn, up_w, up_b, out);
}

// Round 18
// 95.777 us; speedup vs baseline: 2.0307x; 1.1514x over previous
//
#include <hip/hip_runtime.h>
#include <stdint.h>

// Problem constants
#define NB 8
#define HIN 448
#define CH1 256
#define CH2 1024
#define NLOC 1024        // 32*32
#define M2 8192          // NB*NLOC
#define M1 32768         // NB*64*64 conv1 output locations
#define K1 224           // padded im2col K: c*56 + r*8 + cc(0..7), cc==7 -> 0
#define NPTS 12544
#define NOUT 4096
#define CAP 384          // per-batch compacted-row capacity (>= 18*18=324 bound)
#define MC (NB * CAP)    // 3072 compacted conv2 rows
#define M1C (MC * 4)     // 12288 compacted conv1 rows

typedef __attribute__((ext_vector_type(8))) short bf16x8;
typedef __attribute__((ext_vector_type(4))) float f32x4;

__device__ __forceinline__ short f2bf(float f) {
  uint32_t u = __builtin_bit_cast(uint32_t, f);
  uint32_t r = (u + 0x7fffu + ((u >> 16) & 1u)) >> 16;
  return (short)r;
}
__device__ __forceinline__ float bf2f(short s) {
  return __builtin_bit_cast(float, (uint32_t)(uint16_t)s << 16);
}
__device__ __forceinline__ float gelu_f(float x) {
  return 0.5f * x * (1.0f + erff(x * 0.70710678118654752f));
}
__device__ __forceinline__ void gload_lds16(const void* g, void* l) {
  __builtin_amdgcn_global_load_lds((const __attribute__((address_space(1))) unsigned int*)g,
                                   (__attribute__((address_space(3))) unsigned int*)l, 16, 0, 0);
}

// ---- merged: workspace zero + weight cast/permute ----
__global__ void k_prep(const float* __restrict__ c1w, const float* __restrict__ c2w,
                       short* __restrict__ c1wb, short* __restrict__ w2p,
                       float4* __restrict__ zp, int n4) {
  int i = blockIdx.x * 256 + threadIdx.x;
  if (i < n4) zp[i] = make_float4(0.f, 0.f, 0.f, 0.f);
  if (i < CH1 * K1) {
    int o = i / K1, k = i - o * K1;
    int c = k / 56, kk = k - c * 56, r = kk >> 3, cc = kk & 7;
    c1wb[i] = f2bf(cc < 7 ? c1w[((o * 4 + c) * 7 + r) * 7 + cc] : 0.0f);
  }
  if (i < CH2 * CH2) {
    int o = i >> 10, k = i & 1023;
    int pos = k >> 8, ci = k & 255;
    w2p[i] = f2bf(c2w[(size_t)(o * 256 + ci) * 4 + pos]);
  }
}

// ---- point -> bilinear weight accumulation (LDS-aggregated, G12) ----
__global__ __launch_bounds__(256) void k_pts(const float* __restrict__ coords,
                                             float* __restrict__ Aw,
                                             float* __restrict__ cnt,
                                             float* __restrict__ sumAw) {
  __shared__ float lAw[NLOC];
  __shared__ int lcnt;
  __shared__ float wsum[4];
  int t = threadIdx.x;
  int b = blockIdx.x / 49;
  int blk = blockIdx.x - b * 49;
  for (int i = t; i < NLOC; i += 256) lAw[i] = 0.f;
  if (t == 0) lcnt = 0;
  __syncthreads();
  int pi = blk * 256 + t;
  float x = coords[((size_t)b * NPTS + pi) * 2];
  float y = coords[((size_t)b * NPTS + pi) * 2 + 1];
  bool valid = (x >= 0.0f);
  if (valid) {
    float gx = x * 32.0f - 0.5f, gy = y * 32.0f - 0.5f;
    float x0f = floorf(gx), y0f = floorf(gy);
    int x0 = (int)x0f, y0 = (int)y0f;
    float wx1 = gx - x0f, wx0 = 1.0f - wx1;
    float wy1 = gy - y0f, wy0 = 1.0f - wy1;
    int xs[2] = {x0, x0 + 1}, ys[2] = {y0, y0 + 1};
    float wxs[2] = {wx0, wx1}, wys[2] = {wy0, wy1};
    #pragma unroll
    for (int cy = 0; cy < 2; cy++)
      #pragma unroll
      for (int cx = 0; cx < 2; cx++) {
        int ix = xs[cx], iy = ys[cy];
        if (ix >= 0 && ix < 32 && iy >= 0 && iy < 32)
          atomicAdd(&lAw[iy * 32 + ix], wxs[cx] * wys[cy]);
      }
  }
  unsigned long long ball = __ballot(valid);
  if ((t & 63) == 0) atomicAdd(&lcnt, (int)__popcll(ball));
  __syncthreads();
  float tsum = 0.f;
  for (int i = t; i < NLOC; i += 256) {
    float v = lAw[i];
    tsum += v;
    if (v != 0.f) atomicAdd(&Aw[b * NLOC + i], v);
  }
  #pragma unroll
  for (int m = 1; m <= 32; m <<= 1) tsum += __shfl_xor(tsum, m, 64);
  if ((t & 63) == 0) wsum[t >> 6] = tsum;
  __syncthreads();
  if (t == 0) {
    float bs = wsum[0] + wsum[1] + wsum[2] + wsum[3];
    if (bs != 0.f) atomicAdd(&sumAw[b], bs);
    if (lcnt) atomicAdd(&cnt[b], (float)lcnt);
  }
}

// ---- per-batch ordered prefix-scan compaction (8 blocks) ----
__global__ __launch_bounds__(256) void k_compact(const float* __restrict__ Aw,
                                                 int* __restrict__ idxc,
                                                 float* __restrict__ Awc) {
  __shared__ int cnts[256], offs[256];
  int t = threadIdx.x, b = blockIdx.x;
  int base = b * 1024 + t * 4;
  float w[4];
  int c = 0;
  #pragma unroll
  for (int j = 0; j < 4; j++) { w[j] = Aw[base + j]; c += (w[j] != 0.f) ? 1 : 0; }
  cnts[t] = c;
  offs[t] = c;
  __syncthreads();
  for (int s = 1; s < 256; s <<= 1) {
    int v = (t >= s) ? offs[t - s] : 0;
    __syncthreads();
    offs[t] += v;
    __syncthreads();
  }
  int pos = b * CAP + offs[t] - cnts[t];
  int lim = (b + 1) * CAP;
  #pragma unroll
  for (int j = 0; j < 4; j++)
    if (w[j] != 0.f && pos < lim) { idxc[pos] = base + j; Awc[pos] = w[j]; pos++; }
  int total = offs[255];
  for (int i = total + t; i < CAP; i += 256) {
    idxc[b * CAP + i] = b * 1024;
    Awc[b * CAP + i] = 0.f;
  }
}

// ---- gathered im2col: only the 12288 active conv1 rows ----
__global__ __launch_bounds__(256) void k_imc(const int* __restrict__ idxc,
                                             const float* __restrict__ images,
                                             const float* __restrict__ masks,
                                             short* __restrict__ A1c) {
  __shared__ short ct[64 * K1];   // 28K
  int t = threadIdx.x;
  int i0 = blockIdx.x * 16;
  int loc = t >> 4;
  int rem = t & 15;
  int c = rem >> 2, kh = (rem >> 1) & 1, rh = rem & 1;
  int gi = idxc[i0 + loc];
  int b = gi >> 10, oy = (gi >> 5) & 31, ox = gi & 31;
  int yy = oy * 2 + kh;
  int xbase = ox * 14;
  int r0 = rh * 4, rn = rh ? 3 : 4;
  const float* plane = (c < 3)
      ? images + (size_t)(b * 3 + c) * 448 * 448
      : masks + (size_t)b * 448 * 448;
  for (int rr = 0; rr < rn; rr++) {
    int r = r0 + rr;
    const float* src = plane + (size_t)(yy * 7 + r) * 448 + xbase;
    short tmp[14];
    #pragma unroll
    for (int p = 0; p < 7; p++) {
      float2 v = *(const float2*)&src[p * 2];
      tmp[p * 2] = f2bf(v.x);
      tmp[p * 2 + 1] = f2bf(v.y);
    }
    #pragma unroll
    for (int kw = 0; kw < 2; kw++) {
      short* dst = &ct[(loc * 4 + kh * 2 + kw) * K1 + c * 56 + r * 8];
      #pragma unroll
      for (int cc = 0; cc < 7; cc++) dst[cc] = tmp[kw * 7 + cc];
      dst[7] = 0;
    }
  }
  __syncthreads();
  size_t obase = (size_t)blockIdx.x * 64 * K1;
  #pragma unroll
  for (int it = 0; it < 7; it++) {
    int p = it * 256 + t;
    *(bf16x8*)&A1c[obase + (size_t)p * 8] = *(const bf16x8*)&ct[p * 8];
  }
}

// ---- 64x64-tile bf16 BT GEMM (conv1c, linear A) ----
template<int KDIM, int LDC>
__global__ __launch_bounds__(256) void k_gemm64(
    const short* __restrict__ Amat, const short* __restrict__ Bmat,
    const float* __restrict__ bias, short* __restrict__ Cout) {
  __shared__ __align__(16) char Lraw[16384];
  int t = threadIdx.x, lane = t & 63, wv = t >> 6;
  int mt0 = blockIdx.x * 64;
  int nt0 = blockIdx.y * 64;
  f32x4 acc[2][2];
  #pragma unroll
  for (int i = 0; i < 2; i++)
    #pragma unroll
    for (int j = 0; j < 2; j++) acc[i][j] = (f32x4){0.f, 0.f, 0.f, 0.f};

  int srow = lane >> 2, scol = (lane & 3) * 8;
  int wm = wv >> 1, wn = wv & 1;
  int l15 = lane & 15, lg = lane >> 4;

  const short* Ap = Amat + (size_t)(mt0 + wv * 16 + srow) * KDIM;
  const short* Bp = Bmat + (size_t)(nt0 + wv * 16 + srow) * KDIM;

  auto STAGE = [&](int buf, int kt) {
    int k0 = kt * 32;
    char* As = Lraw + buf * 8192;
    char* Bs = As + 4096;
    gload_lds16(Ap + k0 + scol, As + wv * 1024);
    gload_lds16(Bp + k0 + scol, Bs + wv * 1024);
  };

  const int NT = KDIM / 32;
  STAGE(0, 0);
  __syncthreads();
  int cur = 0;
  #pragma unroll 2
  for (int kt = 0; kt < NT; kt++) {
    if (kt + 1 < NT) STAGE(cur ^ 1, kt + 1);
    const short* As = (const short*)(Lraw + cur * 8192);
    const short* Bs = As + 2048;
    bf16x8 af[2], bfr[2];
    #pragma unroll
    for (int i = 0; i < 2; i++)
      af[i] = *(const bf16x8*)&As[(wm * 32 + i * 16 + l15) * 32 + lg * 8];
    #pragma unroll
    for (int j = 0; j < 2; j++)
      bfr[j] = *(const bf16x8*)&Bs[(wn * 32 + j * 16 + l15) * 32 + lg * 8];
    #pragma unroll
    for (int i = 0; i < 2; i++)
      #pragma unroll
      for (int j = 0; j < 2; j++)
        acc[i][j] = __builtin_amdgcn_mfma_f32_16x16x32_bf16(af[i], bfr[j], acc[i][j], 0, 0, 0);
    __syncthreads();
    cur ^= 1;
  }

  short* ct = (short*)Lraw;
  #pragma unroll
  for (int i = 0; i < 2; i++)
    #pragma unroll
    for (int j = 0; j < 2; j++) {
      int cl = wn * 32 + j * 16 + l15;
      float bv = bias[nt0 + cl];
      #pragma unroll
      for (int reg = 0; reg < 4; reg++) {
        int rl = wm * 32 + i * 16 + lg * 4 + reg;
        ct[rl * 68 + cl] = f2bf(acc[i][j][reg] + bv);
      }
    }
  __syncthreads();
  #pragma unroll
  for (int it = 0; it < 2; it++) {
    int p = it * 256 + t;
    int row = p >> 3, cc = (p & 7) * 8;
    bf16x8 v = *(const bf16x8*)&ct[row * 68 + cc];
    *(bf16x8*)&Cout[(size_t)(mt0 + row) * LDC + nt0 + cc] = v;
  }
}

// ---- conv2c: 128x64 tile, K-split + XCD swizzle (768 blocks, 1D grid) ----
__global__ __launch_bounds__(256) void k_gemm2s(
    const short* __restrict__ Amat, const short* __restrict__ Bmat,
    const float* __restrict__ bias, float* __restrict__ y2p0,
    float* __restrict__ y2p1) {
  const int KDIM = 1024;
  __shared__ __align__(16) char Lraw[24576];
  int t = threadIdx.x, lane = t & 63, wv = t >> 6;
  int swz = (blockIdx.x & 7) * 96 + (blockIdx.x >> 3);
  int kz = swz / 384;
  int rem = swz - kz * 384;
  int by = rem / 24;
  int bx = rem - by * 24;
  int mt0 = bx * 128;
  int nt0 = by * 64;
  int kbase = kz * 512;
  float* outp = kz ? y2p1 : y2p0;
  f32x4 acc[4][2];
  #pragma unroll
  for (int i = 0; i < 4; i++)
    #pragma unroll
    for (int j = 0; j < 2; j++) acc[i][j] = (f32x4){0.f, 0.f, 0.f, 0.f};

  int srow = lane >> 2, scol = (lane & 3) * 8;
  int wm = wv >> 1, wn = wv & 1;
  int l15 = lane & 15, lg = lane >> 4;
  int r0 = wv * 16, r1 = 64 + wv * 16;

  auto STAGE = [&](int buf, int kt) {
    int k0 = kbase + kt * 32;
    char* As = Lraw + buf * 12288;
    char* Bs = As + 8192;
    gload_lds16(&Amat[(size_t)(mt0 + r0 + srow) * KDIM + k0 + scol], As + r0 * 64);
    gload_lds16(&Amat[(size_t)(mt0 + r1 + srow) * KDIM + k0 + scol], As + r1 * 64);
    gload_lds16(&Bmat[(size_t)(nt0 + r0 + srow) * KDIM + k0 + scol], Bs + r0 * 64);
  };

  STAGE(0, 0);
  __syncthreads();
  int cur = 0;
  #pragma unroll 2
  for (int kt = 0; kt < 16; kt++) {
    if (kt + 1 < 16) STAGE(cur ^ 1, kt + 1);
    const short* As = (const short*)(Lraw + cur * 12288);
    const short* Bs = As + 4096;
    bf16x8 af[4], bfr[2];
    #pragma unroll
    for (int i = 0; i < 4; i++)
      af[i] = *(const bf16x8*)&As[(wm * 64 + i * 16 + l15) * 32 + lg * 8];
    #pragma unroll
    for (int j = 0; j < 2; j++)
      bfr[j] = *(const bf16x8*)&Bs[(wn * 32 + j * 16 + l15) * 32 + lg * 8];
    #pragma unroll
    for (int i = 0; i < 4; i++)
      #pragma unroll
      for (int j = 0; j < 2; j++)
        acc[i][j] = __builtin_amdgcn_mfma_f32_16x16x32_bf16(af[i], bfr[j], acc[i][j], 0, 0, 0);
    __syncthreads();
    cur ^= 1;
  }

  #pragma unroll
  for (int i = 0; i < 4; i++)
    #pragma unroll
    for (int j = 0; j < 2; j++) {
      int colg = nt0 + wn * 32 + j * 16 + l15;
      float bv = kz ? 0.0f : bias[colg];
      #pragma unroll
      for (int reg = 0; reg < 4; reg++) {
        int rowg = mt0 + wm * 64 + i * 16 + lg * 4 + reg;
        outp[(size_t)rowg * 1024 + colg] = acc[i][j][reg] + bv;
      }
    }
}

// ---- LN(256)+GELU on compacted conv1 rows (linear layout) ----
__global__ __launch_bounds__(256) void k_ln1c(const short* __restrict__ y1c,
                                              const float* __restrict__ ln1w,
                                              const float* __restrict__ ln1b,
                                              short* __restrict__ act1c) {
  int t = threadIdx.x, wv = t >> 6, lane = t & 63;
  int c = lane * 4;
  float lw[4], lb[4];
  #pragma unroll
  for (int j = 0; j < 4; j++) { lw[j] = ln1w[c + j]; lb[j] = ln1b[c + j]; }
  int j0 = blockIdx.x * 64 + wv * 16;
  for (int r = 0; r < 16; r++) {
    int j = j0 + r;
    short4 v4 = *(const short4*)&y1c[(size_t)j * 256 + c];
    float xs[4] = {bf2f(v4.x), bf2f(v4.y), bf2f(v4.z), bf2f(v4.w)};
    float s = 0.f, q = 0.f;
    #pragma unroll
    for (int jj = 0; jj < 4; jj++) { s += xs[jj]; q += xs[jj] * xs[jj]; }
    #pragma unroll
    for (int mm = 1; mm <= 32; mm <<= 1) { s += __shfl_xor(s, mm, 64); q += __shfl_xor(q, mm, 64); }
    float u = s * (1.0f / 256.0f);
    float rs = rsqrtf(q * (1.0f / 256.0f) - u * u + 1e-6f);
    short o[4];
    #pragma unroll
    for (int jj = 0; jj < 4; jj++) o[jj] = f2bf(gelu_f(lw[jj] * ((xs[jj] - u) * rs) + lb[jj]));
    *(short4*)&act1c[(size_t)j * 256 + c] = make_short4(o[0], o[1], o[2], o[3]);
  }
}

// ---- LN2+GELU+pool and feat pool, 384 blocks (8 rows each), atomic-out ----
// 4x the TLP of the old 96-block version; per-block cross-wave LDS combine
// then ONE atomicAdd per channel per block (48 collisions/cell -- the
// proven k_poolf contention profile). Deletes k_red + 12.6 MB round trip.
__global__ __launch_bounds__(256) void k_poolboth(
    const float* __restrict__ y2p0, const float* __restrict__ y2p1,
    const float* __restrict__ feat, const int* __restrict__ idxc,
    const float* __restrict__ ln2w, const float* __restrict__ ln2b,
    const float* __restrict__ Awc, float* __restrict__ pa,
    float* __restrict__ pf) {
  __shared__ float lsA[4][1024];
  __shared__ float lsF[4][1024];
  int t = threadIdx.x, wv = t >> 6, lane = t & 63;
  int b = blockIdx.x / 48, chunk = blockIdx.x % 48;
  int base = b * CAP + chunk * 8;
  int c0 = lane * 16;
  float lw[16], lb[16], wacc[16], facc[16];
  #pragma unroll
  for (int j = 0; j < 16; j++) {
    lw[j] = ln2w[c0 + j];
    lb[j] = ln2b[c0 + j];
    wacc[j] = 0.f;
    facc[j] = 0.f;
  }
  #pragma unroll
  for (int pass = 0; pass < 2; pass++) {
    int row = base + pass * 4 + wv;
    float wt = Awc[row];
    if (wt == 0.f) continue;
    const float4* fp = (const float4*)(feat + (size_t)idxc[row] * 1024 + c0);
    #pragma unroll
    for (int j = 0; j < 4; j++) {
      float4 v = fp[j];
      facc[j * 4 + 0] += wt * v.x;
      facc[j * 4 + 1] += wt * v.y;
      facc[j * 4 + 2] += wt * v.z;
      facc[j * 4 + 3] += wt * v.w;
    }
    const float4* a0 = (const float4*)(y2p0 + (size_t)row * 1024 + c0);
    const float4* a1 = (const float4*)(y2p1 + (size_t)row * 1024 + c0);
    float xs[16];
    #pragma unroll
    for (int j = 0; j < 4; j++) {
      float4 va = a0[j], vb = a1[j];
      xs[j * 4 + 0] = va.x + vb.x;
      xs[j * 4 + 1] = va.y + vb.y;
      xs[j * 4 + 2] = va.z + vb.z;
      xs[j * 4 + 3] = va.w + vb.w;
    }
    float s = 0.f, q = 0.f;
    #pragma unroll
    for (int j = 0; j < 16; j++) { s += xs[j]; q += xs[j] * xs[j]; }
    #pragma unroll
    for (int m = 1; m <= 32; m <<= 1) { s += __shfl_xor(s, m, 64); q += __shfl_xor(q, m, 64); }
    float u = s * (1.0f / 1024.0f);
    float rs = rsqrtf(q * (1.0f / 1024.0f) - u * u + 1e-6f);
    #pragma unroll
    for (int j = 0; j < 16; j++)
      wacc[j] += wt * gelu_f(lw[j] * ((xs[j] - u) * rs) + lb[j]);
  }
  #pragma unroll
  for (int j = 0; j < 4; j++) {
    *(f32x4*)&lsA[wv][c0 + j * 4] = (f32x4){wacc[j * 4], wacc[j * 4 + 1], wacc[j * 4 + 2], wacc[j * 4 + 3]};
    *(f32x4*)&lsF[wv][c0 + j * 4] = (f32x4){facc[j * 4], facc[j * 4 + 1], facc[j * 4 + 2], facc[j * 4 + 3]};
  }
  __syncthreads();
  int cb = t * 4;
  #pragma unroll
  for (int j = 0; j < 4; j++) {
    int c = cb + j;
    float sa = lsA[0][c] + lsA[1][c] + lsA[2][c] + lsA[3][c];
    float sf = lsF[0][c] + lsF[1][c] + lsF[2][c] + lsF[3][c];
    if (sa != 0.f) atomicAdd(&pa[b * 1024 + c], sa);
    if (sf != 0.f) atomicAdd(&pf[b * 1024 + c], sf);
  }
}

// ---- conv3 folded past the pool: wave-per-channel, c3w read once ----
__global__ __launch_bounds__(256) void k_mix(const float* __restrict__ pa,
                                             const float* __restrict__ pf,
                                             const float* __restrict__ sumAw,
                                             const float* __restrict__ cnt,
                                             const float* __restrict__ c3w,
                                             const float* __restrict__ c3b,
                                             float* __restrict__ zn) {
  __shared__ float pl[8192];
  int t = threadIdx.x;
  for (int idx = t; idx < 2048; idx += 256)
    ((float4*)pl)[idx] = ((const float4*)pa)[idx];
  __syncthreads();
  int wv = t >> 6, lane = t & 63;
  int c = blockIdx.x * 4 + wv;
  float w[16];
  #pragma unroll
  for (int i = 0; i < 16; i++) w[i] = c3w[(size_t)c * 1024 + i * 64 + lane];
  float s[8];
  #pragma unroll
  for (int b = 0; b < 8; b++) s[b] = 0.f;
  #pragma unroll
  for (int i = 0; i < 16; i++) {
    int k = i * 64 + lane;
    #pragma unroll
    for (int b = 0; b < 8; b++) s[b] += w[i] * pl[b * 1024 + k];
  }
  #pragma unroll
  for (int m = 1; m <= 32; m <<= 1)
    #pragma unroll
    for (int b = 0; b < 8; b++) s[b] += __shfl_xor(s[b], m, 64);
  if (lane < 8) {
    float cv = cnt[lane];
    float z = s[lane] + sumAw[lane] * c3b[c] + pf[lane * 1024 + c];
    zn[lane * 1024 + c] = cv > 0.f ? z / cv : 0.f;
  }
}

// ---- final GEMV: 1024 blocks, one wave per output row, 8 batches/wave ----
__global__ __launch_bounds__(256) void k_out(const float* __restrict__ zn,
                                             const float* __restrict__ up_w,
                                             const float* __restrict__ up_b,
                                             float* __restrict__ out) {
  __shared__ float pl[8192];
  int t = threadIdx.x;
  for (int idx = t; idx < 2048; idx += 256)
    ((float4*)pl)[idx] = ((const float4*)zn)[idx];
  __syncthreads();
  int wv = t >> 6, lane = t & 63;
  int o = blockIdx.x * 4 + wv;
  float w[16];
  #pragma unroll
  for (int i = 0; i < 16; i++) w[i] = up_w[(size_t)o * 1024 + i * 64 + lane];
  float s[8];
  #pragma unroll
  for (int b = 0; b < 8; b++) s[b] = 0.f;
  #pragma unroll
  for (int i = 0; i < 16; i++) {
    int k = i * 64 + lane;
    #pragma unroll
    for (int b = 0; b < 8; b++) s[b] += w[i] * pl[b * 1024 + k];
  }
  #pragma unroll
  for (int m = 1; m <= 32; m <<= 1)
    #pragma unroll
    for (int b = 0; b < 8; b++) s[b] += __shfl_xor(s[b], m, 64);
  if (lane < 8) out[(size_t)lane * NOUT + o] = s[lane] + up_b[o];
}

extern "C" void kernel_launch(void* const* d_in, const int* in_sizes, int n_in,
                              void* d_out, int out_size, void* d_ws, size_t ws_size,
                              hipStream_t stream) {
  const float* images = (const float*)d_in[0];
  const float* masks  = (const float*)d_in[1];
  const float* feat   = (const float*)d_in[2];
  const float* coords = (const float*)d_in[3];
  const float* c1w  = (const float*)d_in[5];
  const float* c1b  = (const float*)d_in[6];
  const float* ln1w = (const float*)d_in[7];
  const float* ln1b = (const float*)d_in[8];
  const float* c2w  = (const float*)d_in[9];
  const float* c2b  = (const float*)d_in[10];
  const float* ln2w = (const float*)d_in[11];
  const float* ln2b = (const float*)d_in[12];
  const float* c3w  = (const float*)d_in[13];
  const float* c3b  = (const float*)d_in[14];
  const float* up_w = (const float*)d_in[15];
  const float* up_b = (const float*)d_in[16];
  float* out = (float*)d_out;

  char* ws = (char*)d_ws;
  size_t off = 0;
  auto alloc = [&](size_t bytes) -> void* {
    void* p = ws + off;
    off = (off + bytes + 255) & ~(size_t)255;
    return p;
  };
  float* Aw    = (float*)alloc(8192 * 4);
  float* cnt   = (float*)alloc(8 * 4);
  float* sumAw = (float*)alloc(8 * 4);
  float* pa    = (float*)alloc(8192 * 4);   // zeroed; atomic-accumulated
  float* pf    = (float*)alloc(8192 * 4);   // zeroed; atomic-accumulated
  size_t zeroBytes = off;
  int*   idxc  = (int*)alloc(MC * 4);
  float* Awc   = (float*)alloc(MC * 4);
  float* zn   = (float*)alloc(8192 * 4);
  short* c1wb = (short*)alloc((size_t)CH1 * K1 * 2);
  short* w2p  = (short*)alloc((size_t)CH2 * CH2 * 2);
  short* A1c  = (short*)alloc((size_t)M1C * K1 * 2);
  short* y1c  = (short*)alloc((size_t)M1C * 256 * 2);
  short* act1c = (short*)alloc((size_t)MC * 1024 * 2);
  float* y2p0 = (float*)alloc((size_t)MC * 1024 * 4);
  float* y2p1 = (float*)alloc((size_t)MC * 1024 * 4);

  int n4 = (int)(zeroBytes / 16);
  k_prep<<<4096, 256, 0, stream>>>(c1w, c2w, c1wb, w2p, (float4*)d_ws, n4);
  k_pts<<<NB * 49, 256, 0, stream>>>(coords, Aw, cnt, sumAw);
  k_compact<<<NB, 256, 0, stream>>>(Aw, idxc, Awc);
  k_imc<<<MC / 16, 256, 0, stream>>>(idxc, images, masks, A1c);
  k_gemm64<K1, 256><<<dim3(M1C / 64, 4), 256, 0, stream>>>(A1c, c1wb, c1b, y1c);
  k_ln1c<<<M1C / 64, 256, 0, stream>>>(y1c, ln1w, ln1b, act1c);
  k_gemm2s<<<768, 256, 0, stream>>>(act1c, w2p, c2b, y2p0, y2p1);
  k_poolboth<<<384, 256, 0, stream>>>(y2p0, y2p1, feat, idxc, ln2w, ln2b, Awc, pa, pf);
  k_mix<<<256, 256, 0, stream>>>(pa, pf, sumAw, cnt, c3w, c3b, zn);
  k_out<<<NOUT / 4, 256, 0, stream>>>(zn, up_w, up_b, out);
}